// Round 4
// baseline (474.499 us; speedup 1.0000x reference)
//
#include <hip/hip_runtime.h>
#include <hip/hip_bf16.h>

#define S_DIM 4096
#define D_DIM 1024
#define F_DIM 4096

typedef unsigned short ushort_t;
typedef __attribute__((ext_vector_type(8))) short sh8;
typedef __attribute__((ext_vector_type(4))) short sh4;
typedef __attribute__((ext_vector_type(4))) float fx4;

__device__ __forceinline__ ushort_t f2bf(float f) {
    union { float f; unsigned u; } v; v.f = f;
    unsigned r = v.u + 0x7fffu + ((v.u >> 16) & 1u);
    return (ushort_t)(r >> 16);
}
__device__ __forceinline__ float bf2f(ushort_t u) {
    union { unsigned u; float f; } v; v.u = ((unsigned)u) << 16;
    return v.f;
}

typedef const __attribute__((address_space(1))) void* gvp;
typedef __attribute__((address_space(3))) void* svp;
__device__ __forceinline__ void gload_lds16(const void* g, void* l) {
    __builtin_amdgcn_global_load_lds((gvp)g, (svp)l, 16, 0, 0);
}

// ---------------------------------------------------------------------------
// bf16 GEMM body: C[M,N] = A[M,K] @ B[K,N] (+bias) with Bt[N,K] = B^T.
// 128x128 tile, BK=32, 256 threads (4 waves 2x2), mfma_f32_16x16x32_bf16.
// VERIFIED two-barrier K-loop (round-2 structure; replay-race-free).
// Round-3's 2-phase single-barrier variant raced across graph replays —
// do not reintroduce without the full explicit-vmcnt 8-phase template.
// ---------------------------------------------------------------------------
#define BM 128
#define BN 128
#define BK 32

template<bool BIAS, bool RELU, bool SCALE, bool OUTBF, bool SPLITK>
__device__ __forceinline__
void gemm_body(const ushort_t* A, const ushort_t* Bt,
               const float* bias,
               float* Cf, ushort_t* Cb,
               int M, int N, int K, int kBeg, int kEnd, float scale)
{
    __shared__ ushort_t lds[BM * BK + BN * BK];   // 16 KiB
    const int tid = threadIdx.x;
    const int bm = blockIdx.x, bn = blockIdx.y;
    const int w  = tid >> 6, l = tid & 63;
    const int wm = w >> 1, wn = w & 1;

    fx4 acc[4][4] = {};

    const ushort_t* Ag = A  + (size_t)(bm * BM) * K;
    const ushort_t* Bg = Bt + (size_t)(bn * BN) * K;
    char* lbase = (char*)lds;

    for (int k0 = kBeg; k0 < kEnd; k0 += BK) {
        __syncthreads();
        #pragma unroll
        for (int c = 0; c < 2; ++c) {
            int gi  = c * 256 + tid;     // 16B granule index
            int row = gi >> 2;
            int cs  = gi & 3;
            gload_lds16(Ag + (size_t)row * K + k0 + cs * 8,
                        lbase + c * 4096 + tid * 16);
            gload_lds16(Bg + (size_t)row * K + k0 + cs * 8,
                        lbase + 8192 + c * 4096 + tid * 16);
        }
        __syncthreads();

        sh8 af[4], bfr[4];
        #pragma unroll
        for (int t = 0; t < 4; ++t) {
            int ra = wm * 64 + t * 16 + (l & 15);
            af[t]  = *(const sh8*)(lbase + ra * 64 + (l >> 4) * 16);
            int rb = wn * 64 + t * 16 + (l & 15);
            bfr[t] = *(const sh8*)(lbase + 8192 + rb * 64 + (l >> 4) * 16);
        }
        #pragma unroll
        for (int i = 0; i < 4; ++i)
            #pragma unroll
            for (int j = 0; j < 4; ++j)
                acc[i][j] = __builtin_amdgcn_mfma_f32_16x16x32_bf16(
                                af[i], bfr[j], acc[i][j], 0, 0, 0);
    }

    if (SPLITK) Cb += (size_t)blockIdx.z * M * N;

    const int crow0 = bm * BM + wm * 64;
    const int ccol0 = bn * BN + wn * 64;
    #pragma unroll
    for (int i = 0; i < 4; ++i) {
        #pragma unroll
        for (int j = 0; j < 4; ++j) {
            int col = ccol0 + j * 16 + (l & 15);
            float bia = BIAS ? bias[col] : 0.f;
            #pragma unroll
            for (int r = 0; r < 4; ++r) {
                int row = crow0 + i * 16 + (l >> 4) * 4 + r;
                float v = acc[i][j][r] + bia;
                if (SCALE) v *= scale;
                if (RELU) v = fmaxf(v, 0.f);
                if (OUTBF) Cb[(size_t)row * N + col] = f2bf(v);
                else       Cf[(size_t)row * N + col] = v;
            }
        }
    }
}

template<bool BIAS, bool RELU, bool SCALE, bool OUTBF>
__global__ __launch_bounds__(256)
void gemm_bt(const ushort_t* __restrict__ A, const ushort_t* __restrict__ Bt,
             const float* __restrict__ bias,
             float* __restrict__ Cf, ushort_t* __restrict__ Cb,
             int M, int N, int K, float scale)
{
    gemm_body<BIAS, RELU, SCALE, OUTBF, false>(A, Bt, bias, Cf, Cb,
                                               M, N, K, 0, K, scale);
}

// split-K: blockIdx.z = K-slice, bf16 partial per slice
__global__ __launch_bounds__(256)
void gemm_bt_sk(const ushort_t* __restrict__ A, const ushort_t* __restrict__ Bt,
                ushort_t* __restrict__ Cpart, int M, int N, int K, int Ks)
{
    int z = blockIdx.z;
    gemm_body<false, false, false, true, true>(A, Bt, nullptr,
                                               nullptr, Cpart,
                                               M, N, K, z * Ks, z * Ks + Ks, 1.f);
}

// batched q/k/v projection: blockIdx.z selects operand set
__global__ __launch_bounds__(256)
void qkv_gemm(const ushort_t* qin, const ushort_t* kin, const ushort_t* vin,
              const ushort_t* WqT, const ushort_t* WkT, const ushort_t* WvT,
              const float* bq, const float* bk, const float* bv,
              ushort_t* qb, ushort_t* kb, ushort_t* vb, int M, int N, int K)
{
    const ushort_t* A; const ushort_t* Bt; const float* bias; ushort_t* C;
    if (blockIdx.z == 0)      { A = qin; Bt = WqT; bias = bq; C = qb; }
    else if (blockIdx.z == 1) { A = kin; Bt = WkT; bias = bk; C = kb; }
    else                      { A = vin; Bt = WvT; bias = bv; C = vb; }
    gemm_body<true, false, false, true, false>(A, Bt, bias,
                                               nullptr, C, M, N, K, 0, K, 1.f);
}

// sum NS bf16 partial matrices, write bf16
template<int NS>
__global__ __launch_bounds__(256)
void reduce_sk(const ushort_t* __restrict__ parts, ushort_t* __restrict__ ob,
               size_t MN)
{
    size_t idx = ((size_t)blockIdx.x * 256 + threadIdx.x) * 8;
    float s[8] = {0.f, 0.f, 0.f, 0.f, 0.f, 0.f, 0.f, 0.f};
    #pragma unroll
    for (int p = 0; p < NS; ++p) {
        sh8 v = *(const sh8*)(parts + (size_t)p * MN + idx);
        #pragma unroll
        for (int j = 0; j < 8; ++j) s[j] += bf2f((ushort_t)v[j]);
    }
    sh8 r;
    #pragma unroll
    for (int j = 0; j < 8; ++j) r[j] = (short)f2bf(s[j]);
    *(sh8*)(ob + idx) = r;
}

// ---------------------------------------------------------------------------
// fp32 [R][C] -> bf16 [C][R] transpose; batched over 4 weight mats via z
// ---------------------------------------------------------------------------
__global__ __launch_bounds__(256)
void transpose_f32_bf16(const float* __restrict__ in, ushort_t* __restrict__ out,
                        int R, int C)
{
    __shared__ float t[32][33];
    int bc = blockIdx.x * 32, br = blockIdx.y * 32;
    int tx = threadIdx.x & 31, ty = threadIdx.x >> 5;
    #pragma unroll
    for (int i = 0; i < 32; i += 8)
        t[ty + i][tx] = in[(size_t)(br + ty + i) * C + bc + tx];
    __syncthreads();
    #pragma unroll
    for (int i = 0; i < 32; i += 8)
        out[(size_t)(bc + ty + i) * R + br + tx] = f2bf(t[tx][ty + i]);
}

__global__ __launch_bounds__(256)
void transpose4_f32_bf16(const float* w0, const float* w1,
                         const float* w2, const float* w3,
                         ushort_t* o0, ushort_t* o1, ushort_t* o2, ushort_t* o3)
{
    const int R = D_DIM, C = D_DIM;
    const float* in; ushort_t* out;
    if (blockIdx.z == 0)      { in = w0; out = o0; }
    else if (blockIdx.z == 1) { in = w1; out = o1; }
    else if (blockIdx.z == 2) { in = w2; out = o2; }
    else                      { in = w3; out = o3; }
    __shared__ float t[32][33];
    int bc = blockIdx.x * 32, br = blockIdx.y * 32;
    int tx = threadIdx.x & 31, ty = threadIdx.x >> 5;
    #pragma unroll
    for (int i = 0; i < 32; i += 8)
        t[ty + i][tx] = in[(size_t)(br + ty + i) * C + bc + tx];
    __syncthreads();
    #pragma unroll
    for (int i = 0; i < 32; i += 8)
        out[(size_t)(bc + ty + i) * R + br + tx] = f2bf(t[tx][ty + i]);
}

// bf16 [R][C] -> bf16 [C][R] transpose
__global__ __launch_bounds__(256)
void transpose_bf16(const ushort_t* __restrict__ in, ushort_t* __restrict__ out,
                    int R, int C)
{
    __shared__ ushort_t t[32][33];
    int bc = blockIdx.x * 32, br = blockIdx.y * 32;
    int tx = threadIdx.x & 31, ty = threadIdx.x >> 5;
    #pragma unroll
    for (int i = 0; i < 32; i += 8)
        t[ty + i][tx] = in[(size_t)(br + ty + i) * C + bc + tx];
    __syncthreads();
    #pragma unroll
    for (int i = 0; i < 32; i += 8)
        out[(size_t)(bc + ty + i) * R + br + tx] = t[tx][ty + i];
}

// fp32 -> bf16 elementwise, 3 arrays batched via blockIdx.y
__global__ __launch_bounds__(256)
void cvt_bf16_3(const float* a, const float* b, const float* c,
                ushort_t* oa, ushort_t* ob, ushort_t* oc)
{
    const float* in; ushort_t* out;
    if (blockIdx.y == 0)      { in = a; out = oa; }
    else if (blockIdx.y == 1) { in = b; out = ob; }
    else                      { in = c; out = oc; }
    int i = (blockIdx.x * 256 + threadIdx.x) * 8;
    const float4* p = (const float4*)(in + i);
    float4 x = p[0], y = p[1];
    sh8 r;
    r[0] = (short)f2bf(x.x); r[1] = (short)f2bf(x.y);
    r[2] = (short)f2bf(x.z); r[3] = (short)f2bf(x.w);
    r[4] = (short)f2bf(y.x); r[5] = (short)f2bf(y.y);
    r[6] = (short)f2bf(y.z); r[7] = (short)f2bf(y.w);
    *(sh8*)(out + i) = r;
}

// ---------------------------------------------------------------------------
// Column softmax (axis 0) over x = scores*scale (bf16) times mask (f32).
// Mask applied identically in pass1 and pass3 (deterministic recompute).
// ---------------------------------------------------------------------------
#define SM_CH 32

__global__ __launch_bounds__(256)
void smax_pass1(const ushort_t* __restrict__ m, const float* __restrict__ mask,
                float* __restrict__ pmax, float* __restrict__ psum)
{
    int col = blockIdx.x * 256 + threadIdx.x;
    int chunk = blockIdx.y;
    int r0 = chunk * (S_DIM / SM_CH);
    float mx = -1e30f, sm = 0.f;
    for (int i = 0; i < S_DIM / SM_CH; ++i) {
        size_t off = (size_t)(r0 + i) * S_DIM + col;
        float v = bf2f(m[off]) * mask[off];
        if (v > mx) { sm = sm * __expf(mx - v) + 1.f; mx = v; }
        else        { sm += __expf(v - mx); }
    }
    pmax[chunk * S_DIM + col] = mx;
    psum[chunk * S_DIM + col] = sm;
}

__global__ __launch_bounds__(256)
void smax_pass2(const float* __restrict__ pmax, const float* __restrict__ psum,
                float* __restrict__ cmax, float* __restrict__ cinv)
{
    int col = blockIdx.x * 256 + threadIdx.x;
    float mx = -1e30f, sm = 0.f;
    for (int c = 0; c < SM_CH; ++c) {
        float m2 = pmax[c * S_DIM + col];
        float s2 = psum[c * S_DIM + col];
        if (m2 > mx) { sm = sm * __expf(mx - m2) + s2; mx = m2; }
        else         { sm += s2 * __expf(m2 - mx); }
    }
    cmax[col] = mx;
    cinv[col] = 1.f / sm;
}

__global__ __launch_bounds__(256)
void smax_pass3(const ushort_t* __restrict__ m, const float* __restrict__ mask,
                const float* __restrict__ cmax, const float* __restrict__ cinv,
                ushort_t* __restrict__ h)
{
    size_t idx = ((size_t)blockIdx.x * 256 + threadIdx.x) * 8;
    int col0 = (int)(idx & (S_DIM - 1));
    sh8 mv = *(const sh8*)(m + idx);
    float4 mk0 = ((const float4*)(mask + idx))[0];
    float4 mk1 = ((const float4*)(mask + idx))[1];
    float mk[8] = {mk0.x, mk0.y, mk0.z, mk0.w, mk1.x, mk1.y, mk1.z, mk1.w};
    sh8 r;
    #pragma unroll
    for (int j = 0; j < 8; ++j) {
        int c = col0 + j;
        float v = bf2f((ushort_t)mv[j]) * mk[j];
        r[j] = (short)f2bf(__expf(v - cmax[c]) * cinv[c]);
    }
    *(sh8*)(h + idx) = r;
}

// ---------------------------------------------------------------------------
// LayerNorm( sum(parts) + pbias + resid ) over D=1024, one row per block.
// Fuses split-K reduction + bias + residual into the LN.
// ---------------------------------------------------------------------------
template<int NS, bool WB>
__global__ __launch_bounds__(256)
void add_ln_sk(const ushort_t* __restrict__ parts, const float* __restrict__ pbias,
               const float* __restrict__ resid, const float* __restrict__ g,
               const float* __restrict__ be,
               float* __restrict__ of, ushort_t* __restrict__ ob)
{
    const int D = D_DIM;
    const size_t SD = (size_t)S_DIM * D_DIM;
    int row = blockIdx.x, tid = threadIdx.x;
    size_t base = (size_t)row * D + tid * 4;

    float4 vr = *(const float4*)(resid + base);
    float4 vbi = ((const float4*)pbias)[tid];
    float x0 = vr.x + vbi.x, x1 = vr.y + vbi.y, x2 = vr.z + vbi.z, x3 = vr.w + vbi.w;
    #pragma unroll
    for (int p = 0; p < NS; ++p) {
        sh4 v = *(const sh4*)(parts + p * SD + base);
        x0 += bf2f((ushort_t)v[0]); x1 += bf2f((ushort_t)v[1]);
        x2 += bf2f((ushort_t)v[2]); x3 += bf2f((ushort_t)v[3]);
    }

    float s = x0 + x1 + x2 + x3;
    float q = x0 * x0 + x1 * x1 + x2 * x2 + x3 * x3;
    #pragma unroll
    for (int off = 32; off; off >>= 1) {
        s += __shfl_down(s, off);
        q += __shfl_down(q, off);
    }
    __shared__ float red[8];
    int w = tid >> 6, l = tid & 63;
    if (!l) { red[w] = s; red[4 + w] = q; }
    __syncthreads();
    s = red[0] + red[1] + red[2] + red[3];
    q = red[4] + red[5] + red[6] + red[7];
    float mu = s * (1.f / D);
    float rstd = rsqrtf(q * (1.f / D) - mu * mu + 1e-5f);
    float4 vg  = ((const float4*)g)[tid];
    float4 vbe = ((const float4*)be)[tid];
    float y0 = (x0 - mu) * rstd * vg.x + vbe.x;
    float y1 = (x1 - mu) * rstd * vg.y + vbe.y;
    float y2 = (x2 - mu) * rstd * vg.z + vbe.z;
    float y3 = (x3 - mu) * rstd * vg.w + vbe.w;
    float4 r; r.x = y0; r.y = y1; r.z = y2; r.w = y3;
    *(float4*)(of + base) = r;
    if (WB) {
        sh4 rb;
        rb[0] = (short)f2bf(y0); rb[1] = (short)f2bf(y1);
        rb[2] = (short)f2bf(y2); rb[3] = (short)f2bf(y3);
        *(sh4*)(ob + base) = rb;
    }
}

// ---------------------------------------------------------------------------
extern "C" void kernel_launch(void* const* d_in, const int* in_sizes, int n_in,
                              void* d_out, int out_size, void* d_ws, size_t ws_size,
                              hipStream_t stream)
{
    const float* query = (const float*)d_in[0];
    const float* key_  = (const float*)d_in[1];
    const float* value = (const float*)d_in[2];
    const float* mask  = (const float*)d_in[3];
    const float* Wq = (const float*)d_in[4];  const float* bq = (const float*)d_in[5];
    const float* Wk = (const float*)d_in[6];  const float* bk = (const float*)d_in[7];
    const float* Wv = (const float*)d_in[8];  const float* bv = (const float*)d_in[9];
    const float* Wo = (const float*)d_in[10]; const float* bo = (const float*)d_in[11];
    const float* g1 = (const float*)d_in[12]; const float* be1 = (const float*)d_in[13];
    const float* W1 = (const float*)d_in[14]; const float* bf1 = (const float*)d_in[15];
    const float* W2 = (const float*)d_in[16]; const float* bf2 = (const float*)d_in[17];
    const float* g2 = (const float*)d_in[18]; const float* be2 = (const float*)d_in[19];

    const size_t MB = 1ull << 20;
    char* ws = (char*)d_ws;
    ushort_t* WqT = (ushort_t*)(ws);             // [0,2)
    ushort_t* WkT = (ushort_t*)(ws + 2 * MB);    // [2,4)
    ushort_t* WvT = (ushort_t*)(ws + 4 * MB);    // [4,6)
    ushort_t* WoT = (ushort_t*)(ws + 6 * MB);    // [6,8)
    ushort_t* W1T = (ushort_t*)(ws + 8 * MB);    // [8,16)   [F][D]
    ushort_t* W2T = (ushort_t*)(ws + 16 * MB);   // [16,24)  [D][F]
    ushort_t* qin = (ushort_t*)(ws + 24 * MB);   // [24,32)  dead after qkv
    ushort_t* kin = (ushort_t*)(ws + 32 * MB);   // [32,40)  dead after qkv
    ushort_t* vin = (ushort_t*)(ws + 40 * MB);   // [40,48)  dead after qkv
    ushort_t* qb  = (ushort_t*)(ws + 48 * MB);   // [48,56)  dead after QK^T
    ushort_t* kb  = (ushort_t*)(ws + 56 * MB);   // [56,64)  dead after QK^T
    ushort_t* vb  = (ushort_t*)(ws + 64 * MB);   // [64,72)  dead after v-transpose
    ushort_t* vT  = (ushort_t*)(ws + 72 * MB);   // [72,80)  [D][S]
    ushort_t* msc = (ushort_t*)(ws + 80 * MB);   // [80,112) raw scaled scores
    ushort_t* hb  = (ushort_t*)(ws + 112 * MB);  // [112,144) dead after h@v
    float*   pmax = (float*)(ws + 144 * MB);
    float*   psum = (float*)(ws + 144 * MB + 512 * 1024);
    float*   cmax = (float*)(ws + 145 * MB);
    float*   cinv = (float*)(ws + 145 * MB + 64 * 1024);
    // reused regions
    ushort_t* pts1  = (ushort_t*)(ws + 80 * MB); // h@v partials 4x8MB over msc
    ushort_t* apb   = (ushort_t*)(ws + 24 * MB); // attn_pre bf16 over qin
    ushort_t* pts2  = (ushort_t*)(ws + 80 * MB); // attn@Wo partials 2x8MB
    float*    n1f   = (float*)(ws + 48 * MB);    // over qb+kb
    ushort_t* n1b   = (ushort_t*)(ws + 64 * MB); // over vb
    ushort_t* mid   = (ushort_t*)(ws + 112 * MB);// [S][F] bf16 over hb
    ushort_t* pts3  = (ushort_t*)(ws + 80 * MB); // ff partials 4x8MB

    const int S = S_DIM, D = D_DIM, F = F_DIM;

    // 1. weights -> bf16 transposed (4 DxD batched + 2 big)
    transpose4_f32_bf16<<<dim3(D / 32, D / 32, 4), 256, 0, stream>>>(
        Wq, Wk, Wv, Wo, WqT, WkT, WvT, WoT);
    transpose_f32_bf16<<<dim3(F / 32, D / 32), 256, 0, stream>>>(W1, W1T, D, F);
    transpose_f32_bf16<<<dim3(D / 32, F / 32), 256, 0, stream>>>(W2, W2T, F, D);

    // 2. activations -> bf16 (batched)
    cvt_bf16_3<<<dim3(S * D / 8 / 256, 3), 256, 0, stream>>>(
        query, key_, value, qin, kin, vin);

    // 3. batched q,k,v projections (768 blocks)
    qkv_gemm<<<dim3(S / BM, D / BN, 3), 256, 0, stream>>>(
        qin, kin, vin, WqT, WkT, WvT, bq, bk, bv, qb, kb, vb, S, D, D);

    // 4. v^T bf16 [D][S]
    transpose_bf16<<<dim3(D / 32, S / 32), 256, 0, stream>>>(vb, vT, S, D);

    // 5. scaled scores: (q @ k^T) / sqrt(D)   (mask deferred to softmax)
    gemm_bt<false, false, true, true><<<dim3(S / BM, S / BN), 256, 0, stream>>>(
        qb, kb, nullptr, nullptr, msc, S, S, D, 0.03125f);

    // 6. column softmax with fused mask
    smax_pass1<<<dim3(S / 256, SM_CH), 256, 0, stream>>>(msc, mask, pmax, psum);
    smax_pass2<<<S / 256, 256, 0, stream>>>(pmax, psum, cmax, cinv);
    smax_pass3<<<(size_t)S * S / 8 / 256, 256, 0, stream>>>(msc, mask, cmax, cinv, hb);

    // 7. attn_pre = h @ v  — 4-way split-K
    gemm_bt_sk<<<dim3(S / BM, D / BN, 4), 256, 0, stream>>>(hb, vT, pts1, S, D, S, S / 4);
    reduce_sk<4><<<S * D / 2048, 256, 0, stream>>>(pts1, apb, (size_t)S * D);

    // 8. attn partials = attn_pre @ Wo — 2-way split-K (reduction fused in LN1)
    gemm_bt_sk<<<dim3(S / BM, D / BN, 2), 256, 0, stream>>>(apb, WoT, pts2, S, D, D, D / 2);

    // 9. n1 = LN(sum(pts2) + bo + query)
    add_ln_sk<2, true><<<S, 256, 0, stream>>>(pts2, bo, query, g1, be1, n1f, n1b);

    // 10. mid = relu(n1 @ W1 + bf1)
    gemm_bt<true, true, false, true><<<dim3(S / BM, F / BN), 256, 0, stream>>>(
        n1b, W1T, bf1, nullptr, mid, S, F, D, 1.f);

    // 11. ff partials = mid @ W2 — 4-way split-K (reduction fused in LN2)
    gemm_bt_sk<<<dim3(S / BM, D / BN, 4), 256, 0, stream>>>(mid, W2T, pts3, S, D, F, F / 4);

    // 12. out = LN(sum(pts3) + bf2 + n1)
    add_ln_sk<4, false><<<S, 256, 0, stream>>>(pts3, bf2, n1f, g2, be2,
                                               (float*)d_out, nullptr);
}

// Round 5
// 411.786 us; speedup vs baseline: 1.1523x; 1.1523x over previous
//
#include <hip/hip_runtime.h>
#include <hip/hip_bf16.h>

#define S_DIM 4096
#define D_DIM 1024
#define F_DIM 4096

typedef unsigned short ushort_t;
typedef __attribute__((ext_vector_type(8))) short sh8;
typedef __attribute__((ext_vector_type(4))) short sh4;
typedef __attribute__((ext_vector_type(4))) float fx4;

__device__ __forceinline__ ushort_t f2bf(float f) {
    union { float f; unsigned u; } v; v.f = f;
    unsigned r = v.u + 0x7fffu + ((v.u >> 16) & 1u);
    return (ushort_t)(r >> 16);
}
__device__ __forceinline__ float bf2f(ushort_t u) {
    union { unsigned u; float f; } v; v.u = ((unsigned)u) << 16;
    return v.f;
}

typedef const __attribute__((address_space(1))) void* gvp;
typedef __attribute__((address_space(3))) void* svp;
__device__ __forceinline__ void gload_lds16(const void* g, void* l) {
    __builtin_amdgcn_global_load_lds((gvp)g, (svp)l, 16, 0, 0);
}

// ---------------------------------------------------------------------------
// bf16 GEMM body: C[M,N] = A[M,K] @ B[K,N] (+bias) with Bt[N,K] = B^T.
// 128x128 tile, BK=32, 256 threads (4 waves 2x2), mfma_f32_16x16x32_bf16.
// VERIFIED two-barrier K-loop (round-2 structure; replay-race-free).
// Round-3's 2-phase single-barrier variant raced across graph replays —
// do not reintroduce without the full explicit-vmcnt 8-phase template.
// ---------------------------------------------------------------------------
#define BM 128
#define BN 128
#define BK 32

template<bool BIAS, bool RELU, bool SCALE, bool OUTBF, bool SPLITK>
__device__ __forceinline__
void gemm_body(const ushort_t* A, const ushort_t* Bt,
               const float* bias,
               float* Cf, ushort_t* Cb,
               int M, int N, int K, int kBeg, int kEnd, float scale)
{
    __shared__ ushort_t lds[BM * BK + BN * BK];   // 16 KiB
    const int tid = threadIdx.x;
    const int bm = blockIdx.x, bn = blockIdx.y;
    const int w  = tid >> 6, l = tid & 63;
    const int wm = w >> 1, wn = w & 1;

    fx4 acc[4][4] = {};

    const ushort_t* Ag = A  + (size_t)(bm * BM) * K;
    const ushort_t* Bg = Bt + (size_t)(bn * BN) * K;
    char* lbase = (char*)lds;

    for (int k0 = kBeg; k0 < kEnd; k0 += BK) {
        __syncthreads();
        #pragma unroll
        for (int c = 0; c < 2; ++c) {
            int gi  = c * 256 + tid;     // 16B granule index
            int row = gi >> 2;
            int cs  = gi & 3;
            gload_lds16(Ag + (size_t)row * K + k0 + cs * 8,
                        lbase + c * 4096 + tid * 16);
            gload_lds16(Bg + (size_t)row * K + k0 + cs * 8,
                        lbase + 8192 + c * 4096 + tid * 16);
        }
        __syncthreads();

        sh8 af[4], bfr[4];
        #pragma unroll
        for (int t = 0; t < 4; ++t) {
            int ra = wm * 64 + t * 16 + (l & 15);
            af[t]  = *(const sh8*)(lbase + ra * 64 + (l >> 4) * 16);
            int rb = wn * 64 + t * 16 + (l & 15);
            bfr[t] = *(const sh8*)(lbase + 8192 + rb * 64 + (l >> 4) * 16);
        }
        #pragma unroll
        for (int i = 0; i < 4; ++i)
            #pragma unroll
            for (int j = 0; j < 4; ++j)
                acc[i][j] = __builtin_amdgcn_mfma_f32_16x16x32_bf16(
                                af[i], bfr[j], acc[i][j], 0, 0, 0);
    }

    if (SPLITK) Cb += (size_t)blockIdx.z * M * N;

    const int crow0 = bm * BM + wm * 64;
    const int ccol0 = bn * BN + wn * 64;
    #pragma unroll
    for (int i = 0; i < 4; ++i) {
        #pragma unroll
        for (int j = 0; j < 4; ++j) {
            int col = ccol0 + j * 16 + (l & 15);
            float bia = BIAS ? bias[col] : 0.f;
            #pragma unroll
            for (int r = 0; r < 4; ++r) {
                int row = crow0 + i * 16 + (l >> 4) * 4 + r;
                float v = acc[i][j][r] + bia;
                if (SCALE) v *= scale;
                if (RELU) v = fmaxf(v, 0.f);
                if (OUTBF) Cb[(size_t)row * N + col] = f2bf(v);
                else       Cf[(size_t)row * N + col] = v;
            }
        }
    }
}

template<bool BIAS, bool RELU, bool SCALE, bool OUTBF>
__global__ __launch_bounds__(256)
void gemm_bt(const ushort_t* __restrict__ A, const ushort_t* __restrict__ Bt,
             const float* __restrict__ bias,
             float* __restrict__ Cf, ushort_t* __restrict__ Cb,
             int M, int N, int K, float scale)
{
    gemm_body<BIAS, RELU, SCALE, OUTBF, false>(A, Bt, bias, Cf, Cb,
                                               M, N, K, 0, K, scale);
}

// split-K: blockIdx.z = K-slice, bf16 partial per slice
__global__ __launch_bounds__(256)
void gemm_bt_sk(const ushort_t* __restrict__ A, const ushort_t* __restrict__ Bt,
                ushort_t* __restrict__ Cpart, int M, int N, int K, int Ks)
{
    int z = blockIdx.z;
    gemm_body<false, false, false, true, true>(A, Bt, nullptr,
                                               nullptr, Cpart,
                                               M, N, K, z * Ks, z * Ks + Ks, 1.f);
}

// batched q/k/v projection: blockIdx.z selects operand set
__global__ __launch_bounds__(256)
void qkv_gemm(const ushort_t* qin, const ushort_t* kin, const ushort_t* vin,
              const ushort_t* WqT, const ushort_t* WkT, const ushort_t* WvT,
              const float* bq, const float* bk, const float* bv,
              ushort_t* qb, ushort_t* kb, ushort_t* vb, int M, int N, int K)
{
    const ushort_t* A; const ushort_t* Bt; const float* bias; ushort_t* C;
    if (blockIdx.z == 0)      { A = qin; Bt = WqT; bias = bq; C = qb; }
    else if (blockIdx.z == 1) { A = kin; Bt = WkT; bias = bk; C = kb; }
    else                      { A = vin; Bt = WvT; bias = bv; C = vb; }
    gemm_body<true, false, false, true, false>(A, Bt, bias,
                                               nullptr, C, M, N, K, 0, K, 1.f);
}

// sum NS bf16 partial matrices, write bf16
template<int NS>
__global__ __launch_bounds__(256)
void reduce_sk(const ushort_t* __restrict__ parts, ushort_t* __restrict__ ob,
               size_t MN)
{
    size_t idx = ((size_t)blockIdx.x * 256 + threadIdx.x) * 8;
    float s[8] = {0.f, 0.f, 0.f, 0.f, 0.f, 0.f, 0.f, 0.f};
    #pragma unroll
    for (int p = 0; p < NS; ++p) {
        sh8 v = *(const sh8*)(parts + (size_t)p * MN + idx);
        #pragma unroll
        for (int j = 0; j < 8; ++j) s[j] += bf2f((ushort_t)v[j]);
    }
    sh8 r;
    #pragma unroll
    for (int j = 0; j < 8; ++j) r[j] = (short)f2bf(s[j]);
    *(sh8*)(ob + idx) = r;
}

// ---------------------------------------------------------------------------
// fp32 [R][C] -> bf16 [C][R] transpose; batched over 4 weight mats via z
// ---------------------------------------------------------------------------
__global__ __launch_bounds__(256)
void transpose_f32_bf16(const float* __restrict__ in, ushort_t* __restrict__ out,
                        int R, int C)
{
    __shared__ float t[32][33];
    int bc = blockIdx.x * 32, br = blockIdx.y * 32;
    int tx = threadIdx.x & 31, ty = threadIdx.x >> 5;
    #pragma unroll
    for (int i = 0; i < 32; i += 8)
        t[ty + i][tx] = in[(size_t)(br + ty + i) * C + bc + tx];
    __syncthreads();
    #pragma unroll
    for (int i = 0; i < 32; i += 8)
        out[(size_t)(bc + ty + i) * R + br + tx] = f2bf(t[tx][ty + i]);
}

__global__ __launch_bounds__(256)
void transpose4_f32_bf16(const float* w0, const float* w1,
                         const float* w2, const float* w3,
                         ushort_t* o0, ushort_t* o1, ushort_t* o2, ushort_t* o3)
{
    const int R = D_DIM, C = D_DIM;
    const float* in; ushort_t* out;
    if (blockIdx.z == 0)      { in = w0; out = o0; }
    else if (blockIdx.z == 1) { in = w1; out = o1; }
    else if (blockIdx.z == 2) { in = w2; out = o2; }
    else                      { in = w3; out = o3; }
    __shared__ float t[32][33];
    int bc = blockIdx.x * 32, br = blockIdx.y * 32;
    int tx = threadIdx.x & 31, ty = threadIdx.x >> 5;
    #pragma unroll
    for (int i = 0; i < 32; i += 8)
        t[ty + i][tx] = in[(size_t)(br + ty + i) * C + bc + tx];
    __syncthreads();
    #pragma unroll
    for (int i = 0; i < 32; i += 8)
        out[(size_t)(bc + ty + i) * R + br + tx] = f2bf(t[tx][ty + i]);
}

// bf16 [R][C] -> bf16 [C][R] transpose
__global__ __launch_bounds__(256)
void transpose_bf16(const ushort_t* __restrict__ in, ushort_t* __restrict__ out,
                    int R, int C)
{
    __shared__ ushort_t t[32][33];
    int bc = blockIdx.x * 32, br = blockIdx.y * 32;
    int tx = threadIdx.x & 31, ty = threadIdx.x >> 5;
    #pragma unroll
    for (int i = 0; i < 32; i += 8)
        t[ty + i][tx] = in[(size_t)(br + ty + i) * C + bc + tx];
    __syncthreads();
    #pragma unroll
    for (int i = 0; i < 32; i += 8)
        out[(size_t)(bc + ty + i) * R + br + tx] = t[tx][ty + i];
}

// fp32 -> bf16 elementwise, 3 arrays batched via blockIdx.y
__global__ __launch_bounds__(256)
void cvt_bf16_3(const float* a, const float* b, const float* c,
                ushort_t* oa, ushort_t* ob, ushort_t* oc)
{
    const float* in; ushort_t* out;
    if (blockIdx.y == 0)      { in = a; out = oa; }
    else if (blockIdx.y == 1) { in = b; out = ob; }
    else                      { in = c; out = oc; }
    int i = (blockIdx.x * 256 + threadIdx.x) * 8;
    const float4* p = (const float4*)(in + i);
    float4 x = p[0], y = p[1];
    sh8 r;
    r[0] = (short)f2bf(x.x); r[1] = (short)f2bf(x.y);
    r[2] = (short)f2bf(x.z); r[3] = (short)f2bf(x.w);
    r[4] = (short)f2bf(y.x); r[5] = (short)f2bf(y.y);
    r[6] = (short)f2bf(y.z); r[7] = (short)f2bf(y.w);
    *(sh8*)(out + i) = r;
}

// ---------------------------------------------------------------------------
// Column softmax (axis 0) over x = scores*scale (bf16) times mask (f32).
// pass1: 8 cols/thread, vectorized coalesced loads, branchless online
//        softmax over NCH row-chunks; partials stored [col][chunk].
// pass2: one block per column, coalesced partial combine.
// pass3: normalize (vectorized elementwise).
// ---------------------------------------------------------------------------
#define NCH 256
#define ROWS_PER_CH (S_DIM / NCH)   // 16

__global__ __launch_bounds__(256)
void smax_pass1(const ushort_t* __restrict__ m, const float* __restrict__ mask,
                float* __restrict__ pmax, float* __restrict__ psum)
{
    int c0 = (blockIdx.x * 256 + threadIdx.x) * 8;   // 8 columns per thread
    int chunk = blockIdx.y;
    int r0 = chunk * ROWS_PER_CH;

    float mx[8], sm[8];
    #pragma unroll
    for (int j = 0; j < 8; ++j) { mx[j] = -1e30f; sm[j] = 0.f; }

    for (int i = 0; i < ROWS_PER_CH; ++i) {
        size_t off = (size_t)(r0 + i) * S_DIM + c0;
        sh8 mv = *(const sh8*)(m + off);
        float4 k0 = ((const float4*)(mask + off))[0];
        float4 k1 = ((const float4*)(mask + off))[1];
        float mk[8] = {k0.x, k0.y, k0.z, k0.w, k1.x, k1.y, k1.z, k1.w};
        #pragma unroll
        for (int j = 0; j < 8; ++j) {
            float v = bf2f((ushort_t)mv[j]) * mk[j];
            float nm = fmaxf(mx[j], v);
            sm[j] = sm[j] * __expf(mx[j] - nm) + __expf(v - nm);
            mx[j] = nm;
        }
    }
    #pragma unroll
    for (int j = 0; j < 8; ++j) {
        pmax[(size_t)(c0 + j) * NCH + chunk] = mx[j];
        psum[(size_t)(c0 + j) * NCH + chunk] = sm[j];
    }
}

__global__ __launch_bounds__(256)
void smax_pass2(const float* __restrict__ pmax, const float* __restrict__ psum,
                float* __restrict__ cmax, float* __restrict__ cinv)
{
    int col = blockIdx.x, t = threadIdx.x;
    float m = pmax[(size_t)col * NCH + t];
    float s = psum[(size_t)col * NCH + t];

    __shared__ float red[8];
    int w = t >> 6, l = t & 63;

    // block max
    float mx = m;
    #pragma unroll
    for (int off = 32; off; off >>= 1) mx = fmaxf(mx, __shfl_down(mx, off));
    if (!l) red[w] = mx;
    __syncthreads();
    mx = fmaxf(fmaxf(red[0], red[1]), fmaxf(red[2], red[3]));
    __syncthreads();

    // block sum of s * exp(m - mx)
    float sc = s * __expf(m - mx);
    #pragma unroll
    for (int off = 32; off; off >>= 1) sc += __shfl_down(sc, off);
    if (!l) red[4 + w] = sc;
    __syncthreads();
    if (t == 0) {
        float total = red[4] + red[5] + red[6] + red[7];
        cmax[col] = mx;
        cinv[col] = 1.f / total;
    }
}

__global__ __launch_bounds__(256)
void smax_pass3(const ushort_t* __restrict__ m, const float* __restrict__ mask,
                const float* __restrict__ cmax, const float* __restrict__ cinv,
                ushort_t* __restrict__ h)
{
    size_t idx = ((size_t)blockIdx.x * 256 + threadIdx.x) * 8;
    int col0 = (int)(idx & (S_DIM - 1));
    sh8 mv = *(const sh8*)(m + idx);
    float4 mk0 = ((const float4*)(mask + idx))[0];
    float4 mk1 = ((const float4*)(mask + idx))[1];
    float mk[8] = {mk0.x, mk0.y, mk0.z, mk0.w, mk1.x, mk1.y, mk1.z, mk1.w};
    sh8 r;
    #pragma unroll
    for (int j = 0; j < 8; ++j) {
        int c = col0 + j;
        float v = bf2f((ushort_t)mv[j]) * mk[j];
        r[j] = (short)f2bf(__expf(v - cmax[c]) * cinv[c]);
    }
    *(sh8*)(h + idx) = r;
}

// ---------------------------------------------------------------------------
// LayerNorm( sum(parts) + pbias + resid ) over D=1024, one row per block.
// Fuses split-K reduction + bias + residual into the LN.
// ---------------------------------------------------------------------------
template<int NS, bool WB>
__global__ __launch_bounds__(256)
void add_ln_sk(const ushort_t* __restrict__ parts, const float* __restrict__ pbias,
               const float* __restrict__ resid, const float* __restrict__ g,
               const float* __restrict__ be,
               float* __restrict__ of, ushort_t* __restrict__ ob)
{
    const int D = D_DIM;
    const size_t SD = (size_t)S_DIM * D_DIM;
    int row = blockIdx.x, tid = threadIdx.x;
    size_t base = (size_t)row * D + tid * 4;

    float4 vr = *(const float4*)(resid + base);
    float4 vbi = ((const float4*)pbias)[tid];
    float x0 = vr.x + vbi.x, x1 = vr.y + vbi.y, x2 = vr.z + vbi.z, x3 = vr.w + vbi.w;
    #pragma unroll
    for (int p = 0; p < NS; ++p) {
        sh4 v = *(const sh4*)(parts + p * SD + base);
        x0 += bf2f((ushort_t)v[0]); x1 += bf2f((ushort_t)v[1]);
        x2 += bf2f((ushort_t)v[2]); x3 += bf2f((ushort_t)v[3]);
    }

    float s = x0 + x1 + x2 + x3;
    float q = x0 * x0 + x1 * x1 + x2 * x2 + x3 * x3;
    #pragma unroll
    for (int off = 32; off; off >>= 1) {
        s += __shfl_down(s, off);
        q += __shfl_down(q, off);
    }
    __shared__ float red[8];
    int w = tid >> 6, l = tid & 63;
    if (!l) { red[w] = s; red[4 + w] = q; }
    __syncthreads();
    s = red[0] + red[1] + red[2] + red[3];
    q = red[4] + red[5] + red[6] + red[7];
    float mu = s * (1.f / D);
    float rstd = rsqrtf(q * (1.f / D) - mu * mu + 1e-5f);
    float4 vg  = ((const float4*)g)[tid];
    float4 vbe = ((const float4*)be)[tid];
    float y0 = (x0 - mu) * rstd * vg.x + vbe.x;
    float y1 = (x1 - mu) * rstd * vg.y + vbe.y;
    float y2 = (x2 - mu) * rstd * vg.z + vbe.z;
    float y3 = (x3 - mu) * rstd * vg.w + vbe.w;
    float4 r; r.x = y0; r.y = y1; r.z = y2; r.w = y3;
    *(float4*)(of + base) = r;
    if (WB) {
        sh4 rb;
        rb[0] = (short)f2bf(y0); rb[1] = (short)f2bf(y1);
        rb[2] = (short)f2bf(y2); rb[3] = (short)f2bf(y3);
        *(sh4*)(ob + base) = rb;
    }
}

// ---------------------------------------------------------------------------
extern "C" void kernel_launch(void* const* d_in, const int* in_sizes, int n_in,
                              void* d_out, int out_size, void* d_ws, size_t ws_size,
                              hipStream_t stream)
{
    const float* query = (const float*)d_in[0];
    const float* key_  = (const float*)d_in[1];
    const float* value = (const float*)d_in[2];
    const float* mask  = (const float*)d_in[3];
    const float* Wq = (const float*)d_in[4];  const float* bq = (const float*)d_in[5];
    const float* Wk = (const float*)d_in[6];  const float* bk = (const float*)d_in[7];
    const float* Wv = (const float*)d_in[8];  const float* bv = (const float*)d_in[9];
    const float* Wo = (const float*)d_in[10]; const float* bo = (const float*)d_in[11];
    const float* g1 = (const float*)d_in[12]; const float* be1 = (const float*)d_in[13];
    const float* W1 = (const float*)d_in[14]; const float* bf1 = (const float*)d_in[15];
    const float* W2 = (const float*)d_in[16]; const float* bf2 = (const float*)d_in[17];
    const float* g2 = (const float*)d_in[18]; const float* be2 = (const float*)d_in[19];

    const size_t MB = 1ull << 20;
    char* ws = (char*)d_ws;
    ushort_t* WqT = (ushort_t*)(ws);             // [0,2)
    ushort_t* WkT = (ushort_t*)(ws + 2 * MB);    // [2,4)
    ushort_t* WvT = (ushort_t*)(ws + 4 * MB);    // [4,6)
    ushort_t* WoT = (ushort_t*)(ws + 6 * MB);    // [6,8)
    ushort_t* W1T = (ushort_t*)(ws + 8 * MB);    // [8,16)   [F][D]
    ushort_t* W2T = (ushort_t*)(ws + 16 * MB);   // [16,24)  [D][F]
    ushort_t* qin = (ushort_t*)(ws + 24 * MB);   // [24,32)  dead after qkv
    ushort_t* kin = (ushort_t*)(ws + 32 * MB);   // [32,40)  dead after qkv
    ushort_t* vin = (ushort_t*)(ws + 40 * MB);   // [40,48)  dead after qkv
    ushort_t* qb  = (ushort_t*)(ws + 48 * MB);   // [48,56)  dead after QK^T
    ushort_t* kb  = (ushort_t*)(ws + 56 * MB);   // [56,64)  dead after QK^T
    ushort_t* vb  = (ushort_t*)(ws + 64 * MB);   // [64,72)  dead after v-transpose
    ushort_t* vT  = (ushort_t*)(ws + 72 * MB);   // [72,80)  [D][S]
    ushort_t* msc = (ushort_t*)(ws + 80 * MB);   // [80,112) raw scaled scores
    ushort_t* hb  = (ushort_t*)(ws + 112 * MB);  // [112,144) dead after h@v
    float*   pmax = (float*)(ws + 144 * MB);     // [144,148) [S][NCH] f32
    float*   psum = (float*)(ws + 148 * MB);     // [148,152)
    float*   cmax = (float*)(ws + 152 * MB);
    float*   cinv = (float*)(ws + 152 * MB + 64 * 1024);
    // reused regions
    ushort_t* pts1  = (ushort_t*)(ws + 80 * MB); // h@v partials 4x8MB over msc
    ushort_t* apb   = (ushort_t*)(ws + 24 * MB); // attn_pre bf16 over qin
    ushort_t* pts2  = (ushort_t*)(ws + 80 * MB); // attn@Wo partials 2x8MB
    float*    n1f   = (float*)(ws + 48 * MB);    // over qb+kb
    ushort_t* n1b   = (ushort_t*)(ws + 64 * MB); // over vb
    ushort_t* mid   = (ushort_t*)(ws + 112 * MB);// [S][F] bf16 over hb
    ushort_t* pts3  = (ushort_t*)(ws + 80 * MB); // ff partials 4x8MB

    const int S = S_DIM, D = D_DIM, F = F_DIM;

    // 1. weights -> bf16 transposed (4 DxD batched + 2 big)
    transpose4_f32_bf16<<<dim3(D / 32, D / 32, 4), 256, 0, stream>>>(
        Wq, Wk, Wv, Wo, WqT, WkT, WvT, WoT);
    transpose_f32_bf16<<<dim3(F / 32, D / 32), 256, 0, stream>>>(W1, W1T, D, F);
    transpose_f32_bf16<<<dim3(D / 32, F / 32), 256, 0, stream>>>(W2, W2T, F, D);

    // 2. activations -> bf16 (batched)
    cvt_bf16_3<<<dim3(S * D / 8 / 256, 3), 256, 0, stream>>>(
        query, key_, value, qin, kin, vin);

    // 3. batched q,k,v projections (768 blocks)
    qkv_gemm<<<dim3(S / BM, D / BN, 3), 256, 0, stream>>>(
        qin, kin, vin, WqT, WkT, WvT, bq, bk, bv, qb, kb, vb, S, D, D);

    // 4. v^T bf16 [D][S]
    transpose_bf16<<<dim3(D / 32, S / 32), 256, 0, stream>>>(vb, vT, S, D);

    // 5. scaled scores: (q @ k^T) / sqrt(D)   (mask deferred to softmax)
    gemm_bt<false, false, true, true><<<dim3(S / BM, S / BN), 256, 0, stream>>>(
        qb, kb, nullptr, nullptr, msc, S, S, D, 0.03125f);

    // 6. column softmax with fused mask (vectorized, 8 cols/thread)
    smax_pass1<<<dim3(S / 2048, NCH), 256, 0, stream>>>(msc, mask, pmax, psum);
    smax_pass2<<<S, 256, 0, stream>>>(pmax, psum, cmax, cinv);
    smax_pass3<<<(size_t)S * S / 8 / 256, 256, 0, stream>>>(msc, mask, cmax, cinv, hb);

    // 7. attn_pre = h @ v  — 4-way split-K
    gemm_bt_sk<<<dim3(S / BM, D / BN, 4), 256, 0, stream>>>(hb, vT, pts1, S, D, S, S / 4);
    reduce_sk<4><<<S * D / 2048, 256, 0, stream>>>(pts1, apb, (size_t)S * D);

    // 8. attn partials = attn_pre @ Wo — 2-way split-K (reduction fused in LN1)
    gemm_bt_sk<<<dim3(S / BM, D / BN, 2), 256, 0, stream>>>(apb, WoT, pts2, S, D, D, D / 2);

    // 9. n1 = LN(sum(pts2) + bo + query)
    add_ln_sk<2, true><<<S, 256, 0, stream>>>(pts2, bo, query, g1, be1, n1f, n1b);

    // 10. mid = relu(n1 @ W1 + bf1)
    gemm_bt<true, true, false, true><<<dim3(S / BM, F / BN), 256, 0, stream>>>(
        n1b, W1T, bf1, nullptr, mid, S, F, D, 1.f);

    // 11. ff partials = mid @ W2 — 4-way split-K (reduction fused in LN2)
    gemm_bt_sk<<<dim3(S / BM, D / BN, 4), 256, 0, stream>>>(mid, W2T, pts3, S, D, F, F / 4);

    // 12. out = LN(sum(pts3) + bf2 + n1)
    add_ln_sk<4, false><<<S, 256, 0, stream>>>(pts3, bf2, n1f, g2, be2,
                                               (float*)d_out, nullptr);
}

// Round 6
// 382.045 us; speedup vs baseline: 1.2420x; 1.0778x over previous
//
#include <hip/hip_runtime.h>
#include <hip/hip_bf16.h>

#define S_DIM 4096
#define D_DIM 1024
#define F_DIM 4096

typedef unsigned short ushort_t;
typedef __attribute__((ext_vector_type(8))) short sh8;
typedef __attribute__((ext_vector_type(4))) short sh4;
typedef __attribute__((ext_vector_type(4))) float fx4;

__device__ __forceinline__ ushort_t f2bf(float f) {
    union { float f; unsigned u; } v; v.f = f;
    unsigned r = v.u + 0x7fffu + ((v.u >> 16) & 1u);
    return (ushort_t)(r >> 16);
}
__device__ __forceinline__ float bf2f(ushort_t u) {
    union { unsigned u; float f; } v; v.u = ((unsigned)u) << 16;
    return v.f;
}

typedef const __attribute__((address_space(1))) void* gvp;
typedef __attribute__((address_space(3))) void* svp;
__device__ __forceinline__ void gload_lds16(const void* g, void* l) {
    __builtin_amdgcn_global_load_lds((gvp)g, (svp)l, 16, 0, 0);
}

// ---------------------------------------------------------------------------
// bf16 GEMM body: C[M,N] = A[M,K] @ B[K,N] (+bias) with Bt[N,K] = B^T.
// 128x128 tile, BK=32, 256 threads (4 waves 2x2), mfma_f32_16x16x32_bf16.
//
// T3/T4 "minimum 2-phase" pipeline with EXPLICIT drain:
//   iter t: issue stage(t+1) -> ds_read+MFMA on buf[t] -> asm vmcnt(0)
//           (drains stage writes; memory clobber fences LDS reads) ->
//           raw s_barrier -> sched_barrier(0).
// Round-3's race was __syncthreads() NOT emitting the vmcnt(0) drain for the
// cross-iteration global_load_lds->ds_read hazard. The explicit asm wait is
// the fix. Do NOT replace the asm+barrier pair with __syncthreads().
// ---------------------------------------------------------------------------
#define BM 128
#define BN 128
#define BK 32
#define LDS_HALF 16384   // bytes per buffer: A 8KB + B 8KB

template<bool BIAS, bool RELU, bool SCALE, bool OUTBF, bool SPLITK>
__device__ __forceinline__
void gemm_body(const ushort_t* A, const ushort_t* Bt,
               const float* bias,
               float* Cf, ushort_t* Cb,
               int M, int N, int K, int kBeg, int kEnd, float scale)
{
    __shared__ ushort_t lds[2 * (BM * BK + BN * BK)];   // 32 KiB (2 bufs)
    const int tid = threadIdx.x;
    const int bm = blockIdx.x, bn = blockIdx.y;
    const int w  = tid >> 6, l = tid & 63;
    const int wm = w >> 1, wn = w & 1;

    fx4 acc[4][4] = {};

    const ushort_t* Ag = A  + (size_t)(bm * BM) * K;
    const ushort_t* Bg = Bt + (size_t)(bn * BN) * K;

    const int srow = tid >> 2;
    const int scs  = tid & 3;

    auto stage = [&](int b, int k0) {
        char* base = (char*)lds + b * LDS_HALF;
        #pragma unroll
        for (int c = 0; c < 2; ++c) {
            int row = c * 64 + srow;
            gload_lds16(Ag + (size_t)row * K + k0 + scs * 8,
                        base + c * 4096 + tid * 16);
            gload_lds16(Bg + (size_t)row * K + k0 + scs * 8,
                        base + 8192 + c * 4096 + tid * 16);
        }
    };

    const int nt = (kEnd - kBeg) / BK;
    int cur = 0;

    stage(0, kBeg);
    asm volatile("s_waitcnt vmcnt(0)" ::: "memory");
    __builtin_amdgcn_s_barrier();
    __builtin_amdgcn_sched_barrier(0);

    for (int t = 0; t < nt; ++t) {
        if (t + 1 < nt) stage(cur ^ 1, kBeg + (t + 1) * BK);

        char* lbase = (char*)lds + cur * LDS_HALF;
        sh8 af[4], bfr[4];
        #pragma unroll
        for (int q = 0; q < 4; ++q) {
            int ra = wm * 64 + q * 16 + (l & 15);
            af[q]  = *(const sh8*)(lbase + ra * 64 + (l >> 4) * 16);
            int rb = wn * 64 + q * 16 + (l & 15);
            bfr[q] = *(const sh8*)(lbase + 8192 + rb * 64 + (l >> 4) * 16);
        }
        #pragma unroll
        for (int i = 0; i < 4; ++i)
            #pragma unroll
            for (int j = 0; j < 4; ++j)
                acc[i][j] = __builtin_amdgcn_mfma_f32_16x16x32_bf16(
                                af[i], bfr[j], acc[i][j], 0, 0, 0);

        // drain this iter's stage writes; fence LDS reads across the barrier
        asm volatile("s_waitcnt vmcnt(0)" ::: "memory");
        __builtin_amdgcn_s_barrier();
        __builtin_amdgcn_sched_barrier(0);
        cur ^= 1;
    }

    if (SPLITK) Cb += (size_t)blockIdx.z * M * N;

    const int crow0 = bm * BM + wm * 64;
    const int ccol0 = bn * BN + wn * 64;
    #pragma unroll
    for (int i = 0; i < 4; ++i) {
        #pragma unroll
        for (int j = 0; j < 4; ++j) {
            int col = ccol0 + j * 16 + (l & 15);
            float bia = BIAS ? bias[col] : 0.f;
            #pragma unroll
            for (int r = 0; r < 4; ++r) {
                int row = crow0 + i * 16 + (l >> 4) * 4 + r;
                float v = acc[i][j][r] + bia;
                if (SCALE) v *= scale;
                if (RELU) v = fmaxf(v, 0.f);
                if (OUTBF) Cb[(size_t)row * N + col] = f2bf(v);
                else       Cf[(size_t)row * N + col] = v;
            }
        }
    }
}

template<bool BIAS, bool RELU, bool SCALE, bool OUTBF>
__global__ __launch_bounds__(256)
void gemm_bt(const ushort_t* __restrict__ A, const ushort_t* __restrict__ Bt,
             const float* __restrict__ bias,
             float* __restrict__ Cf, ushort_t* __restrict__ Cb,
             int M, int N, int K, float scale)
{
    gemm_body<BIAS, RELU, SCALE, OUTBF, false>(A, Bt, bias, Cf, Cb,
                                               M, N, K, 0, K, scale);
}

// split-K: blockIdx.z = K-slice, bf16 partial per slice
__global__ __launch_bounds__(256)
void gemm_bt_sk(const ushort_t* __restrict__ A, const ushort_t* __restrict__ Bt,
                ushort_t* __restrict__ Cpart, int M, int N, int K, int Ks)
{
    int z = blockIdx.z;
    gemm_body<false, false, false, true, true>(A, Bt, nullptr,
                                               nullptr, Cpart,
                                               M, N, K, z * Ks, z * Ks + Ks, 1.f);
}

// batched q/k/v projection: blockIdx.z selects operand set
__global__ __launch_bounds__(256)
void qkv_gemm(const ushort_t* qin, const ushort_t* kin, const ushort_t* vin,
              const ushort_t* WqT, const ushort_t* WkT, const ushort_t* WvT,
              const float* bq, const float* bk, const float* bv,
              ushort_t* qb, ushort_t* kb, ushort_t* vb, int M, int N, int K)
{
    const ushort_t* A; const ushort_t* Bt; const float* bias; ushort_t* C;
    if (blockIdx.z == 0)      { A = qin; Bt = WqT; bias = bq; C = qb; }
    else if (blockIdx.z == 1) { A = kin; Bt = WkT; bias = bk; C = kb; }
    else                      { A = vin; Bt = WvT; bias = bv; C = vb; }
    gemm_body<true, false, false, true, false>(A, Bt, bias,
                                               nullptr, C, M, N, K, 0, K, 1.f);
}

// sum NS bf16 partial matrices, write bf16
template<int NS>
__global__ __launch_bounds__(256)
void reduce_sk(const ushort_t* __restrict__ parts, ushort_t* __restrict__ ob,
               size_t MN)
{
    size_t idx = ((size_t)blockIdx.x * 256 + threadIdx.x) * 8;
    float s[8] = {0.f, 0.f, 0.f, 0.f, 0.f, 0.f, 0.f, 0.f};
    #pragma unroll
    for (int p = 0; p < NS; ++p) {
        sh8 v = *(const sh8*)(parts + (size_t)p * MN + idx);
        #pragma unroll
        for (int j = 0; j < 8; ++j) s[j] += bf2f((ushort_t)v[j]);
    }
    sh8 r;
    #pragma unroll
    for (int j = 0; j < 8; ++j) r[j] = (short)f2bf(s[j]);
    *(sh8*)(ob + idx) = r;
}

// ---------------------------------------------------------------------------
// fp32 [R][C] -> bf16 [C][R] transpose; batched over 4 weight mats via z
// ---------------------------------------------------------------------------
__global__ __launch_bounds__(256)
void transpose_f32_bf16(const float* __restrict__ in, ushort_t* __restrict__ out,
                        int R, int C)
{
    __shared__ float t[32][33];
    int bc = blockIdx.x * 32, br = blockIdx.y * 32;
    int tx = threadIdx.x & 31, ty = threadIdx.x >> 5;
    #pragma unroll
    for (int i = 0; i < 32; i += 8)
        t[ty + i][tx] = in[(size_t)(br + ty + i) * C + bc + tx];
    __syncthreads();
    #pragma unroll
    for (int i = 0; i < 32; i += 8)
        out[(size_t)(bc + ty + i) * R + br + tx] = f2bf(t[tx][ty + i]);
}

__global__ __launch_bounds__(256)
void transpose4_f32_bf16(const float* w0, const float* w1,
                         const float* w2, const float* w3,
                         ushort_t* o0, ushort_t* o1, ushort_t* o2, ushort_t* o3)
{
    const int R = D_DIM, C = D_DIM;
    const float* in; ushort_t* out;
    if (blockIdx.z == 0)      { in = w0; out = o0; }
    else if (blockIdx.z == 1) { in = w1; out = o1; }
    else if (blockIdx.z == 2) { in = w2; out = o2; }
    else                      { in = w3; out = o3; }
    __shared__ float t[32][33];
    int bc = blockIdx.x * 32, br = blockIdx.y * 32;
    int tx = threadIdx.x & 31, ty = threadIdx.x >> 5;
    #pragma unroll
    for (int i = 0; i < 32; i += 8)
        t[ty + i][tx] = in[(size_t)(br + ty + i) * C + bc + tx];
    __syncthreads();
    #pragma unroll
    for (int i = 0; i < 32; i += 8)
        out[(size_t)(bc + ty + i) * R + br + tx] = f2bf(t[tx][ty + i]);
}

// bf16 [R][C] -> bf16 [C][R] transpose
__global__ __launch_bounds__(256)
void transpose_bf16(const ushort_t* __restrict__ in, ushort_t* __restrict__ out,
                    int R, int C)
{
    __shared__ ushort_t t[32][33];
    int bc = blockIdx.x * 32, br = blockIdx.y * 32;
    int tx = threadIdx.x & 31, ty = threadIdx.x >> 5;
    #pragma unroll
    for (int i = 0; i < 32; i += 8)
        t[ty + i][tx] = in[(size_t)(br + ty + i) * C + bc + tx];
    __syncthreads();
    #pragma unroll
    for (int i = 0; i < 32; i += 8)
        out[(size_t)(bc + ty + i) * R + br + tx] = t[tx][ty + i];
}

// fp32 -> bf16 elementwise, 3 arrays batched via blockIdx.y
__global__ __launch_bounds__(256)
void cvt_bf16_3(const float* a, const float* b, const float* c,
                ushort_t* oa, ushort_t* ob, ushort_t* oc)
{
    const float* in; ushort_t* out;
    if (blockIdx.y == 0)      { in = a; out = oa; }
    else if (blockIdx.y == 1) { in = b; out = ob; }
    else                      { in = c; out = oc; }
    int i = (blockIdx.x * 256 + threadIdx.x) * 8;
    const float4* p = (const float4*)(in + i);
    float4 x = p[0], y = p[1];
    sh8 r;
    r[0] = (short)f2bf(x.x); r[1] = (short)f2bf(x.y);
    r[2] = (short)f2bf(x.z); r[3] = (short)f2bf(x.w);
    r[4] = (short)f2bf(y.x); r[5] = (short)f2bf(y.y);
    r[6] = (short)f2bf(y.z); r[7] = (short)f2bf(y.w);
    *(sh8*)(out + i) = r;
}

// ---------------------------------------------------------------------------
// Column softmax (axis 0) over x = scores*scale (bf16) times mask (f32).
// ---------------------------------------------------------------------------
#define NCH 256
#define ROWS_PER_CH (S_DIM / NCH)   // 16

__global__ __launch_bounds__(256)
void smax_pass1(const ushort_t* __restrict__ m, const float* __restrict__ mask,
                float* __restrict__ pmax, float* __restrict__ psum)
{
    int c0 = (blockIdx.x * 256 + threadIdx.x) * 8;   // 8 columns per thread
    int chunk = blockIdx.y;
    int r0 = chunk * ROWS_PER_CH;

    float mx[8], sm[8];
    #pragma unroll
    for (int j = 0; j < 8; ++j) { mx[j] = -1e30f; sm[j] = 0.f; }

    for (int i = 0; i < ROWS_PER_CH; ++i) {
        size_t off = (size_t)(r0 + i) * S_DIM + c0;
        sh8 mv = *(const sh8*)(m + off);
        float4 k0 = ((const float4*)(mask + off))[0];
        float4 k1 = ((const float4*)(mask + off))[1];
        float mk[8] = {k0.x, k0.y, k0.z, k0.w, k1.x, k1.y, k1.z, k1.w};
        #pragma unroll
        for (int j = 0; j < 8; ++j) {
            float v = bf2f((ushort_t)mv[j]) * mk[j];
            float nm = fmaxf(mx[j], v);
            sm[j] = sm[j] * __expf(mx[j] - nm) + __expf(v - nm);
            mx[j] = nm;
        }
    }
    #pragma unroll
    for (int j = 0; j < 8; ++j) {
        pmax[(size_t)(c0 + j) * NCH + chunk] = mx[j];
        psum[(size_t)(c0 + j) * NCH + chunk] = sm[j];
    }
}

__global__ __launch_bounds__(256)
void smax_pass2(const float* __restrict__ pmax, const float* __restrict__ psum,
                float* __restrict__ cmax, float* __restrict__ cinv)
{
    int col = blockIdx.x, t = threadIdx.x;
    float m = pmax[(size_t)col * NCH + t];
    float s = psum[(size_t)col * NCH + t];

    __shared__ float red[8];
    int w = t >> 6, l = t & 63;

    float mx = m;
    #pragma unroll
    for (int off = 32; off; off >>= 1) mx = fmaxf(mx, __shfl_down(mx, off));
    if (!l) red[w] = mx;
    __syncthreads();
    mx = fmaxf(fmaxf(red[0], red[1]), fmaxf(red[2], red[3]));
    __syncthreads();

    float sc = s * __expf(m - mx);
    #pragma unroll
    for (int off = 32; off; off >>= 1) sc += __shfl_down(sc, off);
    if (!l) red[4 + w] = sc;
    __syncthreads();
    if (t == 0) {
        float total = red[4] + red[5] + red[6] + red[7];
        cmax[col] = mx;
        cinv[col] = 1.f / total;
    }
}

__global__ __launch_bounds__(256)
void smax_pass3(const ushort_t* __restrict__ m, const float* __restrict__ mask,
                const float* __restrict__ cmax, const float* __restrict__ cinv,
                ushort_t* __restrict__ h)
{
    size_t idx = ((size_t)blockIdx.x * 256 + threadIdx.x) * 8;
    int col0 = (int)(idx & (S_DIM - 1));
    sh8 mv = *(const sh8*)(m + idx);
    float4 mk0 = ((const float4*)(mask + idx))[0];
    float4 mk1 = ((const float4*)(mask + idx))[1];
    float mk[8] = {mk0.x, mk0.y, mk0.z, mk0.w, mk1.x, mk1.y, mk1.z, mk1.w};
    sh8 r;
    #pragma unroll
    for (int j = 0; j < 8; ++j) {
        int c = col0 + j;
        float v = bf2f((ushort_t)mv[j]) * mk[j];
        r[j] = (short)f2bf(__expf(v - cmax[c]) * cinv[c]);
    }
    *(sh8*)(h + idx) = r;
}

// ---------------------------------------------------------------------------
// LayerNorm( sum(parts) + pbias + resid ) over D=1024, one row per block.
// ---------------------------------------------------------------------------
template<int NS, bool WB>
__global__ __launch_bounds__(256)
void add_ln_sk(const ushort_t* __restrict__ parts, const float* __restrict__ pbias,
               const float* __restrict__ resid, const float* __restrict__ g,
               const float* __restrict__ be,
               float* __restrict__ of, ushort_t* __restrict__ ob)
{
    const int D = D_DIM;
    const size_t SD = (size_t)S_DIM * D_DIM;
    int row = blockIdx.x, tid = threadIdx.x;
    size_t base = (size_t)row * D + tid * 4;

    float4 vr = *(const float4*)(resid + base);
    float4 vbi = ((const float4*)pbias)[tid];
    float x0 = vr.x + vbi.x, x1 = vr.y + vbi.y, x2 = vr.z + vbi.z, x3 = vr.w + vbi.w;
    #pragma unroll
    for (int p = 0; p < NS; ++p) {
        sh4 v = *(const sh4*)(parts + p * SD + base);
        x0 += bf2f((ushort_t)v[0]); x1 += bf2f((ushort_t)v[1]);
        x2 += bf2f((ushort_t)v[2]); x3 += bf2f((ushort_t)v[3]);
    }

    float s = x0 + x1 + x2 + x3;
    float q = x0 * x0 + x1 * x1 + x2 * x2 + x3 * x3;
    #pragma unroll
    for (int off = 32; off; off >>= 1) {
        s += __shfl_down(s, off);
        q += __shfl_down(q, off);
    }
    __shared__ float red[8];
    int w = tid >> 6, l = tid & 63;
    if (!l) { red[w] = s; red[4 + w] = q; }
    __syncthreads();
    s = red[0] + red[1] + red[2] + red[3];
    q = red[4] + red[5] + red[6] + red[7];
    float mu = s * (1.f / D);
    float rstd = rsqrtf(q * (1.f / D) - mu * mu + 1e-5f);
    float4 vg  = ((const float4*)g)[tid];
    float4 vbe = ((const float4*)be)[tid];
    float y0 = (x0 - mu) * rstd * vg.x + vbe.x;
    float y1 = (x1 - mu) * rstd * vg.y + vbe.y;
    float y2 = (x2 - mu) * rstd * vg.z + vbe.z;
    float y3 = (x3 - mu) * rstd * vg.w + vbe.w;
    float4 r; r.x = y0; r.y = y1; r.z = y2; r.w = y3;
    *(float4*)(of + base) = r;
    if (WB) {
        sh4 rb;
        rb[0] = (short)f2bf(y0); rb[1] = (short)f2bf(y1);
        rb[2] = (short)f2bf(y2); rb[3] = (short)f2bf(y3);
        *(sh4*)(ob + base) = rb;
    }
}

// ---------------------------------------------------------------------------
extern "C" void kernel_launch(void* const* d_in, const int* in_sizes, int n_in,
                              void* d_out, int out_size, void* d_ws, size_t ws_size,
                              hipStream_t stream)
{
    const float* query = (const float*)d_in[0];
    const float* key_  = (const float*)d_in[1];
    const float* value = (const float*)d_in[2];
    const float* mask  = (const float*)d_in[3];
    const float* Wq = (const float*)d_in[4];  const float* bq = (const float*)d_in[5];
    const float* Wk = (const float*)d_in[6];  const float* bk = (const float*)d_in[7];
    const float* Wv = (const float*)d_in[8];  const float* bv = (const float*)d_in[9];
    const float* Wo = (const float*)d_in[10]; const float* bo = (const float*)d_in[11];
    const float* g1 = (const float*)d_in[12]; const float* be1 = (const float*)d_in[13];
    const float* W1 = (const float*)d_in[14]; const float* bf1 = (const float*)d_in[15];
    const float* W2 = (const float*)d_in[16]; const float* bf2 = (const float*)d_in[17];
    const float* g2 = (const float*)d_in[18]; const float* be2 = (const float*)d_in[19];

    const size_t MB = 1ull << 20;
    char* ws = (char*)d_ws;
    ushort_t* WqT = (ushort_t*)(ws);             // [0,2)
    ushort_t* WkT = (ushort_t*)(ws + 2 * MB);    // [2,4)
    ushort_t* WvT = (ushort_t*)(ws + 4 * MB);    // [4,6)
    ushort_t* WoT = (ushort_t*)(ws + 6 * MB);    // [6,8)
    ushort_t* W1T = (ushort_t*)(ws + 8 * MB);    // [8,16)   [F][D]
    ushort_t* W2T = (ushort_t*)(ws + 16 * MB);   // [16,24)  [D][F]
    ushort_t* qin = (ushort_t*)(ws + 24 * MB);   // [24,32)
    ushort_t* kin = (ushort_t*)(ws + 32 * MB);   // [32,40)
    ushort_t* vin = (ushort_t*)(ws + 40 * MB);   // [40,48)
    ushort_t* qb  = (ushort_t*)(ws + 48 * MB);   // [48,56)
    ushort_t* kb  = (ushort_t*)(ws + 56 * MB);   // [56,64)
    ushort_t* vb  = (ushort_t*)(ws + 64 * MB);   // [64,72)
    ushort_t* vT  = (ushort_t*)(ws + 72 * MB);   // [72,80)  [D][S]
    ushort_t* msc = (ushort_t*)(ws + 80 * MB);   // [80,112) raw scaled scores
    ushort_t* hb  = (ushort_t*)(ws + 112 * MB);  // [112,144)
    float*   pmax = (float*)(ws + 144 * MB);     // [144,148) [S][NCH]
    float*   psum = (float*)(ws + 148 * MB);     // [148,152)
    float*   cmax = (float*)(ws + 152 * MB);
    float*   cinv = (float*)(ws + 152 * MB + 64 * 1024);
    // reused regions
    ushort_t* pts1  = (ushort_t*)(ws + 80 * MB); // h@v partials 4x8MB over msc
    ushort_t* apb   = (ushort_t*)(ws + 24 * MB); // attn_pre bf16 over qin
    ushort_t* pts2  = (ushort_t*)(ws + 80 * MB); // attn@Wo partials 2x8MB
    float*    n1f   = (float*)(ws + 48 * MB);    // over qb+kb
    ushort_t* n1b   = (ushort_t*)(ws + 64 * MB); // over vb
    ushort_t* mid   = (ushort_t*)(ws + 112 * MB);// [S][F] bf16 over hb
    ushort_t* pts3  = (ushort_t*)(ws + 80 * MB); // ff partials 4x8MB

    const int S = S_DIM, D = D_DIM, F = F_DIM;

    // 1. weights -> bf16 transposed
    transpose4_f32_bf16<<<dim3(D / 32, D / 32, 4), 256, 0, stream>>>(
        Wq, Wk, Wv, Wo, WqT, WkT, WvT, WoT);
    transpose_f32_bf16<<<dim3(F / 32, D / 32), 256, 0, stream>>>(W1, W1T, D, F);
    transpose_f32_bf16<<<dim3(D / 32, F / 32), 256, 0, stream>>>(W2, W2T, F, D);

    // 2. activations -> bf16
    cvt_bf16_3<<<dim3(S * D / 8 / 256, 3), 256, 0, stream>>>(
        query, key_, value, qin, kin, vin);

    // 3. batched q,k,v projections
    qkv_gemm<<<dim3(S / BM, D / BN, 3), 256, 0, stream>>>(
        qin, kin, vin, WqT, WkT, WvT, bq, bk, bv, qb, kb, vb, S, D, D);

    // 4. v^T bf16 [D][S]
    transpose_bf16<<<dim3(D / 32, S / 32), 256, 0, stream>>>(vb, vT, S, D);

    // 5. scaled scores: (q @ k^T) / sqrt(D)
    gemm_bt<false, false, true, true><<<dim3(S / BM, S / BN), 256, 0, stream>>>(
        qb, kb, nullptr, nullptr, msc, S, S, D, 0.03125f);

    // 6. column softmax with fused mask
    smax_pass1<<<dim3(S / 2048, NCH), 256, 0, stream>>>(msc, mask, pmax, psum);
    smax_pass2<<<S, 256, 0, stream>>>(pmax, psum, cmax, cinv);
    smax_pass3<<<(size_t)S * S / 8 / 256, 256, 0, stream>>>(msc, mask, cmax, cinv, hb);

    // 7. attn_pre = h @ v  — 4-way split-K
    gemm_bt_sk<<<dim3(S / BM, D / BN, 4), 256, 0, stream>>>(hb, vT, pts1, S, D, S, S / 4);
    reduce_sk<4><<<S * D / 2048, 256, 0, stream>>>(pts1, apb, (size_t)S * D);

    // 8. attn partials = attn_pre @ Wo — 2-way split-K (reduction fused in LN1)
    gemm_bt_sk<<<dim3(S / BM, D / BN, 2), 256, 0, stream>>>(apb, WoT, pts2, S, D, D, D / 2);

    // 9. n1 = LN(sum(pts2) + bo + query)
    add_ln_sk<2, true><<<S, 256, 0, stream>>>(pts2, bo, query, g1, be1, n1f, n1b);

    // 10. mid = relu(n1 @ W1 + bf1)
    gemm_bt<true, true, false, true><<<dim3(S / BM, F / BN), 256, 0, stream>>>(
        n1b, W1T, bf1, nullptr, mid, S, F, D, 1.f);

    // 11. ff partials = mid @ W2 — 4-way split-K (reduction fused in LN2)
    gemm_bt_sk<<<dim3(S / BM, D / BN, 4), 256, 0, stream>>>(mid, W2T, pts3, S, D, F, F / 4);

    // 12. out = LN(sum(pts3) + bf2 + n1)
    add_ln_sk<4, false><<<S, 256, 0, stream>>>(pts3, bf2, n1f, g2, be2,
                                               (float*)d_out, nullptr);
}

// Round 7
// 365.549 us; speedup vs baseline: 1.2980x; 1.0451x over previous
//
#include <hip/hip_runtime.h>
#include <hip/hip_bf16.h>

#define S_DIM 4096
#define D_DIM 1024
#define F_DIM 4096

typedef unsigned short ushort_t;
typedef __attribute__((ext_vector_type(8))) short sh8;
typedef __attribute__((ext_vector_type(4))) short sh4;
typedef __attribute__((ext_vector_type(4))) float fx4;

__device__ __forceinline__ ushort_t f2bf(float f) {
    union { float f; unsigned u; } v; v.f = f;
    unsigned r = v.u + 0x7fffu + ((v.u >> 16) & 1u);
    return (ushort_t)(r >> 16);
}
__device__ __forceinline__ float bf2f(ushort_t u) {
    union { unsigned u; float f; } v; v.u = ((unsigned)u) << 16;
    return v.f;
}

typedef const __attribute__((address_space(1))) void* gvp;
typedef __attribute__((address_space(3))) void* svp;
__device__ __forceinline__ void gload_lds16(const void* g, void* l) {
    __builtin_amdgcn_global_load_lds((gvp)g, (svp)l, 16, 0, 0);
}

// ---------------------------------------------------------------------------
// bf16 GEMM body: C[M,N] = A[M,K] @ B[K,N] (+bias) with Bt[N,K] = B^T.
// 128x128 tile, BK=32, 256 threads (4 waves 2x2), mfma_f32_16x16x32_bf16.
//
// T3+T4 pipeline: 3 LDS buffers, stage issued 2 K-steps ahead, ONE barrier
// per K-step, steady-state wait = vmcnt(4) (never 0 mid-loop).
//   iter t: stage(buf[(t+2)%3], t+2)          // overwrite: read at t-1,
//                                             //  fenced by end-of-(t-1) barrier
//           ds_read+MFMA on buf[t%3]
//           lgkmcnt(0)                        // reads landed before overwrite
//           vmcnt(4)                          // stage(t+1) done; stage(t+2) in flight
//           s_barrier; sched_barrier(0)       // pin next iter below barrier
// Round-3 lesson: __syncthreads() does NOT emit the vmcnt drain for the
// cross-iteration global_load_lds->ds_read hazard — all waits are explicit asm.
// ---------------------------------------------------------------------------
#define BM 128
#define BN 128
#define BK 32
#define LDS_BUF 16384   // bytes per buffer: A 8KB + B 8KB

template<bool BIAS, bool RELU, bool SCALE, bool OUTBF, bool SPLITK>
__device__ __forceinline__
void gemm_body(const ushort_t* A, const ushort_t* Bt,
               const float* bias,
               float* Cf, ushort_t* Cb,
               int M, int N, int K, int kBeg, int kEnd, float scale)
{
    __shared__ ushort_t lds[3 * (BM * BK + BN * BK)];   // 48 KiB (3 bufs)
    const int tid = threadIdx.x;
    const int bm = blockIdx.x, bn = blockIdx.y;
    const int w  = tid >> 6, l = tid & 63;
    const int wm = w >> 1, wn = w & 1;

    fx4 acc[4][4] = {};

    const ushort_t* Ag = A  + (size_t)(bm * BM) * K;
    const ushort_t* Bg = Bt + (size_t)(bn * BN) * K;

    const int srow = tid >> 2;
    const int scs  = tid & 3;

    auto stage = [&](int b, int k0) {
        char* base = (char*)lds + b * LDS_BUF;
        #pragma unroll
        for (int c = 0; c < 2; ++c) {
            int row = c * 64 + srow;
            gload_lds16(Ag + (size_t)row * K + k0 + scs * 8,
                        base + c * 4096 + tid * 16);
            gload_lds16(Bg + (size_t)row * K + k0 + scs * 8,
                        base + 8192 + c * 4096 + tid * 16);
        }
    };

    const int nt = (kEnd - kBeg) / BK;

    // prologue: stage tiles 0 and 1; wait only for tile 0
    stage(0, kBeg);
    if (nt > 1) {
        stage(1, kBeg + BK);
        asm volatile("s_waitcnt vmcnt(4)" ::: "memory");
    } else {
        asm volatile("s_waitcnt vmcnt(0)" ::: "memory");
    }
    __builtin_amdgcn_s_barrier();
    __builtin_amdgcn_sched_barrier(0);

    int cur = 0;
    for (int t = 0; t < nt; ++t) {
        // issue prefetch for tile t+2 into the buffer consumed at iter t-1
        int stg = cur + 2; if (stg >= 3) stg -= 3;
        if (t + 2 < nt) stage(stg, kBeg + (t + 2) * BK);

        char* lbase = (char*)lds + cur * LDS_BUF;
        sh8 af[4], bfr[4];
        #pragma unroll
        for (int q = 0; q < 4; ++q) {
            int ra = wm * 64 + q * 16 + (l & 15);
            af[q]  = *(const sh8*)(lbase + ra * 64 + (l >> 4) * 16);
            int rb = wn * 64 + q * 16 + (l & 15);
            bfr[q] = *(const sh8*)(lbase + 8192 + rb * 64 + (l >> 4) * 16);
        }
        #pragma unroll
        for (int i = 0; i < 4; ++i)
            #pragma unroll
            for (int j = 0; j < 4; ++j)
                acc[i][j] = __builtin_amdgcn_mfma_f32_16x16x32_bf16(
                                af[i], bfr[j], acc[i][j], 0, 0, 0);

        // this wave's LDS reads must land before buf[cur] is overwritten at t+2
        asm volatile("s_waitcnt lgkmcnt(0)" ::: "memory");
        // wait for tile t+1's stage (issued at t-1); keep t+2's in flight
        if (t + 2 < nt)      asm volatile("s_waitcnt vmcnt(4)" ::: "memory");
        else if (t + 1 < nt) asm volatile("s_waitcnt vmcnt(0)" ::: "memory");
        if (t + 1 < nt) {
            __builtin_amdgcn_s_barrier();
            __builtin_amdgcn_sched_barrier(0);
        }
        cur = cur + 1; if (cur == 3) cur = 0;
    }

    if (SPLITK) Cb += (size_t)blockIdx.z * M * N;

    const int crow0 = bm * BM + wm * 64;
    const int ccol0 = bn * BN + wn * 64;
    #pragma unroll
    for (int i = 0; i < 4; ++i) {
        #pragma unroll
        for (int j = 0; j < 4; ++j) {
            int col = ccol0 + j * 16 + (l & 15);
            float bia = BIAS ? bias[col] : 0.f;
            #pragma unroll
            for (int r = 0; r < 4; ++r) {
                int row = crow0 + i * 16 + (l >> 4) * 4 + r;
                float v = acc[i][j][r] + bia;
                if (SCALE) v *= scale;
                if (RELU) v = fmaxf(v, 0.f);
                if (OUTBF) Cb[(size_t)row * N + col] = f2bf(v);
                else       Cf[(size_t)row * N + col] = v;
            }
        }
    }
}

template<bool BIAS, bool RELU, bool SCALE, bool OUTBF>
__global__ __launch_bounds__(256)
void gemm_bt(const ushort_t* __restrict__ A, const ushort_t* __restrict__ Bt,
             const float* __restrict__ bias,
             float* __restrict__ Cf, ushort_t* __restrict__ Cb,
             int M, int N, int K, float scale)
{
    gemm_body<BIAS, RELU, SCALE, OUTBF, false>(A, Bt, bias, Cf, Cb,
                                               M, N, K, 0, K, scale);
}

// split-K: blockIdx.z = K-slice, bf16 partial per slice
__global__ __launch_bounds__(256)
void gemm_bt_sk(const ushort_t* __restrict__ A, const ushort_t* __restrict__ Bt,
                ushort_t* __restrict__ Cpart, int M, int N, int K, int Ks)
{
    int z = blockIdx.z;
    gemm_body<false, false, false, true, true>(A, Bt, nullptr,
                                               nullptr, Cpart,
                                               M, N, K, z * Ks, z * Ks + Ks, 1.f);
}

// batched q/k/v projection: blockIdx.z selects operand set
__global__ __launch_bounds__(256)
void qkv_gemm(const ushort_t* qin, const ushort_t* kin, const ushort_t* vin,
              const ushort_t* WqT, const ushort_t* WkT, const ushort_t* WvT,
              const float* bq, const float* bk, const float* bv,
              ushort_t* qb, ushort_t* kb, ushort_t* vb, int M, int N, int K)
{
    const ushort_t* A; const ushort_t* Bt; const float* bias; ushort_t* C;
    if (blockIdx.z == 0)      { A = qin; Bt = WqT; bias = bq; C = qb; }
    else if (blockIdx.z == 1) { A = kin; Bt = WkT; bias = bk; C = kb; }
    else                      { A = vin; Bt = WvT; bias = bv; C = vb; }
    gemm_body<true, false, false, true, false>(A, Bt, bias,
                                               nullptr, C, M, N, K, 0, K, 1.f);
}

// sum NS bf16 partial matrices, write bf16
template<int NS>
__global__ __launch_bounds__(256)
void reduce_sk(const ushort_t* __restrict__ parts, ushort_t* __restrict__ ob,
               size_t MN)
{
    size_t idx = ((size_t)blockIdx.x * 256 + threadIdx.x) * 8;
    float s[8] = {0.f, 0.f, 0.f, 0.f, 0.f, 0.f, 0.f, 0.f};
    #pragma unroll
    for (int p = 0; p < NS; ++p) {
        sh8 v = *(const sh8*)(parts + (size_t)p * MN + idx);
        #pragma unroll
        for (int j = 0; j < 8; ++j) s[j] += bf2f((ushort_t)v[j]);
    }
    sh8 r;
    #pragma unroll
    for (int j = 0; j < 8; ++j) r[j] = (short)f2bf(s[j]);
    *(sh8*)(ob + idx) = r;
}

// ---------------------------------------------------------------------------
// fp32 [R][C] -> bf16 [C][R] transpose; batched over 4 weight mats via z
// ---------------------------------------------------------------------------
__global__ __launch_bounds__(256)
void transpose_f32_bf16(const float* __restrict__ in, ushort_t* __restrict__ out,
                        int R, int C)
{
    __shared__ float t[32][33];
    int bc = blockIdx.x * 32, br = blockIdx.y * 32;
    int tx = threadIdx.x & 31, ty = threadIdx.x >> 5;
    #pragma unroll
    for (int i = 0; i < 32; i += 8)
        t[ty + i][tx] = in[(size_t)(br + ty + i) * C + bc + tx];
    __syncthreads();
    #pragma unroll
    for (int i = 0; i < 32; i += 8)
        out[(size_t)(bc + ty + i) * R + br + tx] = f2bf(t[tx][ty + i]);
}

__global__ __launch_bounds__(256)
void transpose4_f32_bf16(const float* w0, const float* w1,
                         const float* w2, const float* w3,
                         ushort_t* o0, ushort_t* o1, ushort_t* o2, ushort_t* o3)
{
    const int R = D_DIM, C = D_DIM;
    const float* in; ushort_t* out;
    if (blockIdx.z == 0)      { in = w0; out = o0; }
    else if (blockIdx.z == 1) { in = w1; out = o1; }
    else if (blockIdx.z == 2) { in = w2; out = o2; }
    else                      { in = w3; out = o3; }
    __shared__ float t[32][33];
    int bc = blockIdx.x * 32, br = blockIdx.y * 32;
    int tx = threadIdx.x & 31, ty = threadIdx.x >> 5;
    #pragma unroll
    for (int i = 0; i < 32; i += 8)
        t[ty + i][tx] = in[(size_t)(br + ty + i) * C + bc + tx];
    __syncthreads();
    #pragma unroll
    for (int i = 0; i < 32; i += 8)
        out[(size_t)(bc + ty + i) * R + br + tx] = f2bf(t[tx][ty + i]);
}

// bf16 [R][C] -> bf16 [C][R] transpose
__global__ __launch_bounds__(256)
void transpose_bf16(const ushort_t* __restrict__ in, ushort_t* __restrict__ out,
                    int R, int C)
{
    __shared__ ushort_t t[32][33];
    int bc = blockIdx.x * 32, br = blockIdx.y * 32;
    int tx = threadIdx.x & 31, ty = threadIdx.x >> 5;
    #pragma unroll
    for (int i = 0; i < 32; i += 8)
        t[ty + i][tx] = in[(size_t)(br + ty + i) * C + bc + tx];
    __syncthreads();
    #pragma unroll
    for (int i = 0; i < 32; i += 8)
        out[(size_t)(bc + ty + i) * R + br + tx] = t[tx][ty + i];
}

// fp32 -> bf16 elementwise, 3 arrays batched via blockIdx.y
__global__ __launch_bounds__(256)
void cvt_bf16_3(const float* a, const float* b, const float* c,
                ushort_t* oa, ushort_t* ob, ushort_t* oc)
{
    const float* in; ushort_t* out;
    if (blockIdx.y == 0)      { in = a; out = oa; }
    else if (blockIdx.y == 1) { in = b; out = ob; }
    else                      { in = c; out = oc; }
    int i = (blockIdx.x * 256 + threadIdx.x) * 8;
    const float4* p = (const float4*)(in + i);
    float4 x = p[0], y = p[1];
    sh8 r;
    r[0] = (short)f2bf(x.x); r[1] = (short)f2bf(x.y);
    r[2] = (short)f2bf(x.z); r[3] = (short)f2bf(x.w);
    r[4] = (short)f2bf(y.x); r[5] = (short)f2bf(y.y);
    r[6] = (short)f2bf(y.z); r[7] = (short)f2bf(y.w);
    *(sh8*)(out + i) = r;
}

// ---------------------------------------------------------------------------
// Column softmax (axis 0) over x = scores*scale (bf16) times mask (f32).
// ---------------------------------------------------------------------------
#define NCH 256
#define ROWS_PER_CH (S_DIM / NCH)   // 16

__global__ __launch_bounds__(256)
void smax_pass1(const ushort_t* __restrict__ m, const float* __restrict__ mask,
                float* __restrict__ pmax, float* __restrict__ psum)
{
    int c0 = (blockIdx.x * 256 + threadIdx.x) * 8;   // 8 columns per thread
    int chunk = blockIdx.y;
    int r0 = chunk * ROWS_PER_CH;

    float mx[8], sm[8];
    #pragma unroll
    for (int j = 0; j < 8; ++j) { mx[j] = -1e30f; sm[j] = 0.f; }

    for (int i = 0; i < ROWS_PER_CH; ++i) {
        size_t off = (size_t)(r0 + i) * S_DIM + c0;
        sh8 mv = *(const sh8*)(m + off);
        float4 k0 = ((const float4*)(mask + off))[0];
        float4 k1 = ((const float4*)(mask + off))[1];
        float mk[8] = {k0.x, k0.y, k0.z, k0.w, k1.x, k1.y, k1.z, k1.w};
        #pragma unroll
        for (int j = 0; j < 8; ++j) {
            float v = bf2f((ushort_t)mv[j]) * mk[j];
            float nm = fmaxf(mx[j], v);
            sm[j] = sm[j] * __expf(mx[j] - nm) + __expf(v - nm);
            mx[j] = nm;
        }
    }
    #pragma unroll
    for (int j = 0; j < 8; ++j) {
        pmax[(size_t)(c0 + j) * NCH + chunk] = mx[j];
        psum[(size_t)(c0 + j) * NCH + chunk] = sm[j];
    }
}

__global__ __launch_bounds__(256)
void smax_pass2(const float* __restrict__ pmax, const float* __restrict__ psum,
                float* __restrict__ cmax, float* __restrict__ cinv)
{
    int col = blockIdx.x, t = threadIdx.x;
    float m = pmax[(size_t)col * NCH + t];
    float s = psum[(size_t)col * NCH + t];

    __shared__ float red[8];
    int w = t >> 6, l = t & 63;

    float mx = m;
    #pragma unroll
    for (int off = 32; off; off >>= 1) mx = fmaxf(mx, __shfl_down(mx, off));
    if (!l) red[w] = mx;
    __syncthreads();
    mx = fmaxf(fmaxf(red[0], red[1]), fmaxf(red[2], red[3]));
    __syncthreads();

    float sc = s * __expf(m - mx);
    #pragma unroll
    for (int off = 32; off; off >>= 1) sc += __shfl_down(sc, off);
    if (!l) red[4 + w] = sc;
    __syncthreads();
    if (t == 0) {
        float total = red[4] + red[5] + red[6] + red[7];
        cmax[col] = mx;
        cinv[col] = 1.f / total;
    }
}

__global__ __launch_bounds__(256)
void smax_pass3(const ushort_t* __restrict__ m, const float* __restrict__ mask,
                const float* __restrict__ cmax, const float* __restrict__ cinv,
                ushort_t* __restrict__ h)
{
    size_t idx = ((size_t)blockIdx.x * 256 + threadIdx.x) * 8;
    int col0 = (int)(idx & (S_DIM - 1));
    sh8 mv = *(const sh8*)(m + idx);
    float4 mk0 = ((const float4*)(mask + idx))[0];
    float4 mk1 = ((const float4*)(mask + idx))[1];
    float mk[8] = {mk0.x, mk0.y, mk0.z, mk0.w, mk1.x, mk1.y, mk1.z, mk1.w};
    sh8 r;
    #pragma unroll
    for (int j = 0; j < 8; ++j) {
        int c = col0 + j;
        float v = bf2f((ushort_t)mv[j]) * mk[j];
        r[j] = (short)f2bf(__expf(v - cmax[c]) * cinv[c]);
    }
    *(sh8*)(h + idx) = r;
}

// ---------------------------------------------------------------------------
// LayerNorm( sum(parts) + pbias + resid ) over D=1024, one row per block.
// ---------------------------------------------------------------------------
template<int NS, bool WB>
__global__ __launch_bounds__(256)
void add_ln_sk(const ushort_t* __restrict__ parts, const float* __restrict__ pbias,
               const float* __restrict__ resid, const float* __restrict__ g,
               const float* __restrict__ be,
               float* __restrict__ of, ushort_t* __restrict__ ob)
{
    const int D = D_DIM;
    const size_t SD = (size_t)S_DIM * D_DIM;
    int row = blockIdx.x, tid = threadIdx.x;
    size_t base = (size_t)row * D + tid * 4;

    float4 vr = *(const float4*)(resid + base);
    float4 vbi = ((const float4*)pbias)[tid];
    float x0 = vr.x + vbi.x, x1 = vr.y + vbi.y, x2 = vr.z + vbi.z, x3 = vr.w + vbi.w;
    #pragma unroll
    for (int p = 0; p < NS; ++p) {
        sh4 v = *(const sh4*)(parts + p * SD + base);
        x0 += bf2f((ushort_t)v[0]); x1 += bf2f((ushort_t)v[1]);
        x2 += bf2f((ushort_t)v[2]); x3 += bf2f((ushort_t)v[3]);
    }

    float s = x0 + x1 + x2 + x3;
    float q = x0 * x0 + x1 * x1 + x2 * x2 + x3 * x3;
    #pragma unroll
    for (int off = 32; off; off >>= 1) {
        s += __shfl_down(s, off);
        q += __shfl_down(q, off);
    }
    __shared__ float red[8];
    int w = tid >> 6, l = tid & 63;
    if (!l) { red[w] = s; red[4 + w] = q; }
    __syncthreads();
    s = red[0] + red[1] + red[2] + red[3];
    q = red[4] + red[5] + red[6] + red[7];
    float mu = s * (1.f / D);
    float rstd = rsqrtf(q * (1.f / D) - mu * mu + 1e-5f);
    float4 vg  = ((const float4*)g)[tid];
    float4 vbe = ((const float4*)be)[tid];
    float y0 = (x0 - mu) * rstd * vg.x + vbe.x;
    float y1 = (x1 - mu) * rstd * vg.y + vbe.y;
    float y2 = (x2 - mu) * rstd * vg.z + vbe.z;
    float y3 = (x3 - mu) * rstd * vg.w + vbe.w;
    float4 r; r.x = y0; r.y = y1; r.z = y2; r.w = y3;
    *(float4*)(of + base) = r;
    if (WB) {
        sh4 rb;
        rb[0] = (short)f2bf(y0); rb[1] = (short)f2bf(y1);
        rb[2] = (short)f2bf(y2); rb[3] = (short)f2bf(y3);
        *(sh4*)(ob + base) = rb;
    }
}

// ---------------------------------------------------------------------------
extern "C" void kernel_launch(void* const* d_in, const int* in_sizes, int n_in,
                              void* d_out, int out_size, void* d_ws, size_t ws_size,
                              hipStream_t stream)
{
    const float* query = (const float*)d_in[0];
    const float* key_  = (const float*)d_in[1];
    const float* value = (const float*)d_in[2];
    const float* mask  = (const float*)d_in[3];
    const float* Wq = (const float*)d_in[4];  const float* bq = (const float*)d_in[5];
    const float* Wk = (const float*)d_in[6];  const float* bk = (const float*)d_in[7];
    const float* Wv = (const float*)d_in[8];  const float* bv = (const float*)d_in[9];
    const float* Wo = (const float*)d_in[10]; const float* bo = (const float*)d_in[11];
    const float* g1 = (const float*)d_in[12]; const float* be1 = (const float*)d_in[13];
    const float* W1 = (const float*)d_in[14]; const float* bf1 = (const float*)d_in[15];
    const float* W2 = (const float*)d_in[16]; const float* bf2 = (const float*)d_in[17];
    const float* g2 = (const float*)d_in[18]; const float* be2 = (const float*)d_in[19];

    const size_t MB = 1ull << 20;
    char* ws = (char*)d_ws;
    ushort_t* WqT = (ushort_t*)(ws);             // [0,2)
    ushort_t* WkT = (ushort_t*)(ws + 2 * MB);    // [2,4)
    ushort_t* WvT = (ushort_t*)(ws + 4 * MB);    // [4,6)
    ushort_t* WoT = (ushort_t*)(ws + 6 * MB);    // [6,8)
    ushort_t* W1T = (ushort_t*)(ws + 8 * MB);    // [8,16)   [F][D]
    ushort_t* W2T = (ushort_t*)(ws + 16 * MB);   // [16,24)  [D][F]
    ushort_t* qin = (ushort_t*)(ws + 24 * MB);   // [24,32)
    ushort_t* kin = (ushort_t*)(ws + 32 * MB);   // [32,40)
    ushort_t* vin = (ushort_t*)(ws + 40 * MB);   // [40,48)
    ushort_t* qb  = (ushort_t*)(ws + 48 * MB);   // [48,56)
    ushort_t* kb  = (ushort_t*)(ws + 56 * MB);   // [56,64)
    ushort_t* vb  = (ushort_t*)(ws + 64 * MB);   // [64,72)
    ushort_t* vT  = (ushort_t*)(ws + 72 * MB);   // [72,80)  [D][S]
    ushort_t* msc = (ushort_t*)(ws + 80 * MB);   // [80,112) raw scaled scores
    ushort_t* hb  = (ushort_t*)(ws + 112 * MB);  // [112,144)
    float*   pmax = (float*)(ws + 144 * MB);     // [144,148) [S][NCH]
    float*   psum = (float*)(ws + 148 * MB);     // [148,152)
    float*   cmax = (float*)(ws + 152 * MB);
    float*   cinv = (float*)(ws + 152 * MB + 64 * 1024);
    // reused regions
    ushort_t* pts1  = (ushort_t*)(ws + 80 * MB); // h@v partials 4x8MB over msc
    ushort_t* apb   = (ushort_t*)(ws + 24 * MB); // attn_pre bf16 over qin
    ushort_t* pts2  = (ushort_t*)(ws + 80 * MB); // attn@Wo partials 2x8MB
    float*    n1f   = (float*)(ws + 48 * MB);    // over qb+kb
    ushort_t* n1b   = (ushort_t*)(ws + 64 * MB); // over vb
    ushort_t* mid   = (ushort_t*)(ws + 112 * MB);// [S][F] bf16 over hb
    ushort_t* pts3  = (ushort_t*)(ws + 80 * MB); // ff partials 4x8MB

    const int S = S_DIM, D = D_DIM, F = F_DIM;

    // 1. weights -> bf16 transposed
    transpose4_f32_bf16<<<dim3(D / 32, D / 32, 4), 256, 0, stream>>>(
        Wq, Wk, Wv, Wo, WqT, WkT, WvT, WoT);
    transpose_f32_bf16<<<dim3(F / 32, D / 32), 256, 0, stream>>>(W1, W1T, D, F);
    transpose_f32_bf16<<<dim3(D / 32, F / 32), 256, 0, stream>>>(W2, W2T, F, D);

    // 2. activations -> bf16
    cvt_bf16_3<<<dim3(S * D / 8 / 256, 3), 256, 0, stream>>>(
        query, key_, value, qin, kin, vin);

    // 3. batched q,k,v projections
    qkv_gemm<<<dim3(S / BM, D / BN, 3), 256, 0, stream>>>(
        qin, kin, vin, WqT, WkT, WvT, bq, bk, bv, qb, kb, vb, S, D, D);

    // 4. v^T bf16 [D][S]
    transpose_bf16<<<dim3(D / 32, S / 32), 256, 0, stream>>>(vb, vT, S, D);

    // 5. scaled scores: (q @ k^T) / sqrt(D)
    gemm_bt<false, false, true, true><<<dim3(S / BM, S / BN), 256, 0, stream>>>(
        qb, kb, nullptr, nullptr, msc, S, S, D, 0.03125f);

    // 6. column softmax with fused mask
    smax_pass1<<<dim3(S / 2048, NCH), 256, 0, stream>>>(msc, mask, pmax, psum);
    smax_pass2<<<S, 256, 0, stream>>>(pmax, psum, cmax, cinv);
    smax_pass3<<<(size_t)S * S / 8 / 256, 256, 0, stream>>>(msc, mask, cmax, cinv, hb);

    // 7. attn_pre = h @ v  — 4-way split-K
    gemm_bt_sk<<<dim3(S / BM, D / BN, 4), 256, 0, stream>>>(hb, vT, pts1, S, D, S, S / 4);
    reduce_sk<4><<<S * D / 2048, 256, 0, stream>>>(pts1, apb, (size_t)S * D);

    // 8. attn partials = attn_pre @ Wo — 2-way split-K (reduction fused in LN1)
    gemm_bt_sk<<<dim3(S / BM, D / BN, 2), 256, 0, stream>>>(apb, WoT, pts2, S, D, D, D / 2);

    // 9. n1 = LN(sum(pts2) + bo + query)
    add_ln_sk<2, true><<<S, 256, 0, stream>>>(pts2, bo, query, g1, be1, n1f, n1b);

    // 10. mid = relu(n1 @ W1 + bf1)
    gemm_bt<true, true, false, true><<<dim3(S / BM, F / BN), 256, 0, stream>>>(
        n1b, W1T, bf1, nullptr, mid, S, F, D, 1.f);

    // 11. ff partials = mid @ W2 — 4-way split-K (reduction fused in LN2)
    gemm_bt_sk<<<dim3(S / BM, D / BN, 4), 256, 0, stream>>>(mid, W2T, pts3, S, D, F, F / 4);

    // 12. out = LN(sum(pts3) + bf2 + n1)
    add_ln_sk<4, false><<<S, 256, 0, stream>>>(pts3, bf2, n1f, g2, be2,
                                               (float*)d_out, nullptr);
}

// Round 8
// 358.625 us; speedup vs baseline: 1.3231x; 1.0193x over previous
//
#include <hip/hip_runtime.h>
#include <hip/hip_bf16.h>

#define S_DIM 4096
#define D_DIM 1024
#define F_DIM 4096

typedef unsigned short ushort_t;
typedef __attribute__((ext_vector_type(8))) short sh8;
typedef __attribute__((ext_vector_type(4))) short sh4;
typedef __attribute__((ext_vector_type(4))) float fx4;

__device__ __forceinline__ ushort_t f2bf(float f) {
    union { float f; unsigned u; } v; v.f = f;
    unsigned r = v.u + 0x7fffu + ((v.u >> 16) & 1u);
    return (ushort_t)(r >> 16);
}
__device__ __forceinline__ float bf2f(ushort_t u) {
    union { unsigned u; float f; } v; v.u = ((unsigned)u) << 16;
    return v.f;
}

typedef const __attribute__((address_space(1))) void* gvp;
typedef __attribute__((address_space(3))) void* svp;
__device__ __forceinline__ void gload_lds16(const void* g, void* l) {
    __builtin_amdgcn_global_load_lds((gvp)g, (svp)l, 16, 0, 0);
}

// ---------------------------------------------------------------------------
// bf16 GEMM body: C[M,N] = A[M,K] @ B[K,N] (+bias) with Bt[N,K] = B^T.
// 128x128 tile, BK=32, 256 threads (4 waves 2x2), mfma_f32_16x16x32_bf16.
//
// T3+T4 pipeline (round-7 verified): 3 LDS buffers, stage 2 K-steps ahead,
// one barrier per K-step, steady-state wait vmcnt(4). All waits explicit asm
// (round-3 lesson: __syncthreads does NOT drain the cross-iter
// global_load_lds->ds_read hazard).
//
// T2 LDS XOR swizzle (round-8): physical 16B-chunk = logical ^ (row&3),
// applied BOTH sides (rule #21): linear LDS dest + pre-swizzled GLOBAL
// source chunk in stage(), same XOR on the ds_read address. Lane still
// receives logical k-chunk (l>>4) -> MFMA inputs bitwise unchanged.
// Breaks the 8-way bank conflict (row stride 64B, 16 lanes/chunk) to 4-way.
// ---------------------------------------------------------------------------
#define BM 128
#define BN 128
#define BK 32
#define LDS_BUF 16384   // bytes per buffer: A 8KB + B 8KB

template<bool BIAS, bool RELU, bool SCALE, bool OUTBF, bool SPLITK>
__device__ __forceinline__
void gemm_body(const ushort_t* A, const ushort_t* Bt,
               const float* bias,
               float* Cf, ushort_t* Cb,
               int M, int N, int K, int kBeg, int kEnd, float scale)
{
    __shared__ ushort_t lds[3 * (BM * BK + BN * BK)];   // 48 KiB (3 bufs)
    const int tid = threadIdx.x;
    const int bm = blockIdx.x, bn = blockIdx.y;
    const int w  = tid >> 6, l = tid & 63;
    const int wm = w >> 1, wn = w & 1;

    fx4 acc[4][4] = {};

    const ushort_t* Ag = A  + (size_t)(bm * BM) * K;
    const ushort_t* Bg = Bt + (size_t)(bn * BN) * K;

    const int srow = tid >> 2;
    const int scs  = (tid & 3) ^ (srow & 3);   // pre-swizzled global chunk

    auto stage = [&](int b, int k0) {
        char* base = (char*)lds + b * LDS_BUF;
        #pragma unroll
        for (int c = 0; c < 2; ++c) {
            int row = c * 64 + srow;           // row&3 == srow&3
            gload_lds16(Ag + (size_t)row * K + k0 + scs * 8,
                        base + c * 4096 + tid * 16);
            gload_lds16(Bg + (size_t)row * K + k0 + scs * 8,
                        base + 8192 + c * 4096 + tid * 16);
        }
    };

    const int nt = (kEnd - kBeg) / BK;

    // prologue: stage tiles 0 and 1; wait only for tile 0
    stage(0, kBeg);
    if (nt > 1) {
        stage(1, kBeg + BK);
        asm volatile("s_waitcnt vmcnt(4)" ::: "memory");
    } else {
        asm volatile("s_waitcnt vmcnt(0)" ::: "memory");
    }
    __builtin_amdgcn_s_barrier();
    __builtin_amdgcn_sched_barrier(0);

    int cur = 0;
    for (int t = 0; t < nt; ++t) {
        // issue prefetch for tile t+2 into the buffer consumed at iter t-1
        int stg = cur + 2; if (stg >= 3) stg -= 3;
        if (t + 2 < nt) stage(stg, kBeg + (t + 2) * BK);

        char* lbase = (char*)lds + cur * LDS_BUF;
        sh8 af[4], bfr[4];
        #pragma unroll
        for (int q = 0; q < 4; ++q) {
            int ra = wm * 64 + q * 16 + (l & 15);
            int ca = (l >> 4) ^ (ra & 3);      // swizzled physical chunk
            af[q]  = *(const sh8*)(lbase + ra * 64 + ca * 16);
            int rb = wn * 64 + q * 16 + (l & 15);
            int cb = (l >> 4) ^ (rb & 3);
            bfr[q] = *(const sh8*)(lbase + 8192 + rb * 64 + cb * 16);
        }
        #pragma unroll
        for (int i = 0; i < 4; ++i)
            #pragma unroll
            for (int j = 0; j < 4; ++j)
                acc[i][j] = __builtin_amdgcn_mfma_f32_16x16x32_bf16(
                                af[i], bfr[j], acc[i][j], 0, 0, 0);

        // this wave's LDS reads must land before buf[cur] is overwritten at t+2
        asm volatile("s_waitcnt lgkmcnt(0)" ::: "memory");
        // wait for tile t+1's stage (issued at t-1); keep t+2's in flight
        if (t + 2 < nt)      asm volatile("s_waitcnt vmcnt(4)" ::: "memory");
        else if (t + 1 < nt) asm volatile("s_waitcnt vmcnt(0)" ::: "memory");
        if (t + 1 < nt) {
            __builtin_amdgcn_s_barrier();
            __builtin_amdgcn_sched_barrier(0);
        }
        cur = cur + 1; if (cur == 3) cur = 0;
    }

    if (SPLITK) Cb += (size_t)blockIdx.z * M * N;

    const int crow0 = bm * BM + wm * 64;
    const int ccol0 = bn * BN + wn * 64;
    #pragma unroll
    for (int i = 0; i < 4; ++i) {
        #pragma unroll
        for (int j = 0; j < 4; ++j) {
            int col = ccol0 + j * 16 + (l & 15);
            float bia = BIAS ? bias[col] : 0.f;
            #pragma unroll
            for (int r = 0; r < 4; ++r) {
                int row = crow0 + i * 16 + (l >> 4) * 4 + r;
                float v = acc[i][j][r] + bia;
                if (SCALE) v *= scale;
                if (RELU) v = fmaxf(v, 0.f);
                if (OUTBF) Cb[(size_t)row * N + col] = f2bf(v);
                else       Cf[(size_t)row * N + col] = v;
            }
        }
    }
}

template<bool BIAS, bool RELU, bool SCALE, bool OUTBF>
__global__ __launch_bounds__(256)
void gemm_bt(const ushort_t* __restrict__ A, const ushort_t* __restrict__ Bt,
             const float* __restrict__ bias,
             float* __restrict__ Cf, ushort_t* __restrict__ Cb,
             int M, int N, int K, float scale)
{
    gemm_body<BIAS, RELU, SCALE, OUTBF, false>(A, Bt, bias, Cf, Cb,
                                               M, N, K, 0, K, scale);
}

// split-K: blockIdx.z = K-slice, bf16 partial per slice
__global__ __launch_bounds__(256)
void gemm_bt_sk(const ushort_t* __restrict__ A, const ushort_t* __restrict__ Bt,
                ushort_t* __restrict__ Cpart, int M, int N, int K, int Ks)
{
    int z = blockIdx.z;
    gemm_body<false, false, false, true, true>(A, Bt, nullptr,
                                               nullptr, Cpart,
                                               M, N, K, z * Ks, z * Ks + Ks, 1.f);
}

// batched q/k/v projection: blockIdx.z selects operand set
__global__ __launch_bounds__(256)
void qkv_gemm(const ushort_t* qin, const ushort_t* kin, const ushort_t* vin,
              const ushort_t* WqT, const ushort_t* WkT, const ushort_t* WvT,
              const float* bq, const float* bk, const float* bv,
              ushort_t* qb, ushort_t* kb, ushort_t* vb, int M, int N, int K)
{
    const ushort_t* A; const ushort_t* Bt; const float* bias; ushort_t* C;
    if (blockIdx.z == 0)      { A = qin; Bt = WqT; bias = bq; C = qb; }
    else if (blockIdx.z == 1) { A = kin; Bt = WkT; bias = bk; C = kb; }
    else                      { A = vin; Bt = WvT; bias = bv; C = vb; }
    gemm_body<true, false, false, true, false>(A, Bt, bias,
                                               nullptr, C, M, N, K, 0, K, 1.f);
}

// sum NS bf16 partial matrices, write bf16
template<int NS>
__global__ __launch_bounds__(256)
void reduce_sk(const ushort_t* __restrict__ parts, ushort_t* __restrict__ ob,
               size_t MN)
{
    size_t idx = ((size_t)blockIdx.x * 256 + threadIdx.x) * 8;
    float s[8] = {0.f, 0.f, 0.f, 0.f, 0.f, 0.f, 0.f, 0.f};
    #pragma unroll
    for (int p = 0; p < NS; ++p) {
        sh8 v = *(const sh8*)(parts + (size_t)p * MN + idx);
        #pragma unroll
        for (int j = 0; j < 8; ++j) s[j] += bf2f((ushort_t)v[j]);
    }
    sh8 r;
    #pragma unroll
    for (int j = 0; j < 8; ++j) r[j] = (short)f2bf(s[j]);
    *(sh8*)(ob + idx) = r;
}

// ---------------------------------------------------------------------------
// fp32 [R][C] -> bf16 [C][R] transpose; batched over 4 weight mats via z
// ---------------------------------------------------------------------------
__global__ __launch_bounds__(256)
void transpose_f32_bf16(const float* __restrict__ in, ushort_t* __restrict__ out,
                        int R, int C)
{
    __shared__ float t[32][33];
    int bc = blockIdx.x * 32, br = blockIdx.y * 32;
    int tx = threadIdx.x & 31, ty = threadIdx.x >> 5;
    #pragma unroll
    for (int i = 0; i < 32; i += 8)
        t[ty + i][tx] = in[(size_t)(br + ty + i) * C + bc + tx];
    __syncthreads();
    #pragma unroll
    for (int i = 0; i < 32; i += 8)
        out[(size_t)(bc + ty + i) * R + br + tx] = f2bf(t[tx][ty + i]);
}

__global__ __launch_bounds__(256)
void transpose4_f32_bf16(const float* w0, const float* w1,
                         const float* w2, const float* w3,
                         ushort_t* o0, ushort_t* o1, ushort_t* o2, ushort_t* o3)
{
    const int R = D_DIM, C = D_DIM;
    const float* in; ushort_t* out;
    if (blockIdx.z == 0)      { in = w0; out = o0; }
    else if (blockIdx.z == 1) { in = w1; out = o1; }
    else if (blockIdx.z == 2) { in = w2; out = o2; }
    else                      { in = w3; out = o3; }
    __shared__ float t[32][33];
    int bc = blockIdx.x * 32, br = blockIdx.y * 32;
    int tx = threadIdx.x & 31, ty = threadIdx.x >> 5;
    #pragma unroll
    for (int i = 0; i < 32; i += 8)
        t[ty + i][tx] = in[(size_t)(br + ty + i) * C + bc + tx];
    __syncthreads();
    #pragma unroll
    for (int i = 0; i < 32; i += 8)
        out[(size_t)(bc + ty + i) * R + br + tx] = f2bf(t[tx][ty + i]);
}

// bf16 [R][C] -> bf16 [C][R] transpose
__global__ __launch_bounds__(256)
void transpose_bf16(const ushort_t* __restrict__ in, ushort_t* __restrict__ out,
                    int R, int C)
{
    __shared__ ushort_t t[32][33];
    int bc = blockIdx.x * 32, br = blockIdx.y * 32;
    int tx = threadIdx.x & 31, ty = threadIdx.x >> 5;
    #pragma unroll
    for (int i = 0; i < 32; i += 8)
        t[ty + i][tx] = in[(size_t)(br + ty + i) * C + bc + tx];
    __syncthreads();
    #pragma unroll
    for (int i = 0; i < 32; i += 8)
        out[(size_t)(bc + ty + i) * R + br + tx] = t[tx][ty + i];
}

// fp32 -> bf16 elementwise, 3 arrays batched via blockIdx.y
__global__ __launch_bounds__(256)
void cvt_bf16_3(const float* a, const float* b, const float* c,
                ushort_t* oa, ushort_t* ob, ushort_t* oc)
{
    const float* in; ushort_t* out;
    if (blockIdx.y == 0)      { in = a; out = oa; }
    else if (blockIdx.y == 1) { in = b; out = ob; }
    else                      { in = c; out = oc; }
    int i = (blockIdx.x * 256 + threadIdx.x) * 8;
    const float4* p = (const float4*)(in + i);
    float4 x = p[0], y = p[1];
    sh8 r;
    r[0] = (short)f2bf(x.x); r[1] = (short)f2bf(x.y);
    r[2] = (short)f2bf(x.z); r[3] = (short)f2bf(x.w);
    r[4] = (short)f2bf(y.x); r[5] = (short)f2bf(y.y);
    r[6] = (short)f2bf(y.z); r[7] = (short)f2bf(y.w);
    *(sh8*)(out + i) = r;
}

// ---------------------------------------------------------------------------
// Column softmax (axis 0). pass1 applies mask*scale, writes the masked value
// back IN PLACE (bf16, per-thread read-then-write of the same 16B) and keeps
// the online max/sum; pass3 then needs only the masked matrix (no mask read).
// ---------------------------------------------------------------------------
#define NCH 256
#define ROWS_PER_CH (S_DIM / NCH)   // 16

__global__ __launch_bounds__(256)
void smax_pass1(ushort_t* __restrict__ m, const float* __restrict__ mask,
                float* __restrict__ pmax, float* __restrict__ psum)
{
    int c0 = (blockIdx.x * 256 + threadIdx.x) * 8;   // 8 columns per thread
    int chunk = blockIdx.y;
    int r0 = chunk * ROWS_PER_CH;

    float mx[8], sm[8];
    #pragma unroll
    for (int j = 0; j < 8; ++j) { mx[j] = -1e30f; sm[j] = 0.f; }

    for (int i = 0; i < ROWS_PER_CH; ++i) {
        size_t off = (size_t)(r0 + i) * S_DIM + c0;
        sh8 mv = *(const sh8*)(m + off);
        float4 k0 = ((const float4*)(mask + off))[0];
        float4 k1 = ((const float4*)(mask + off))[1];
        float mk[8] = {k0.x, k0.y, k0.z, k0.w, k1.x, k1.y, k1.z, k1.w};
        sh8 wv;
        #pragma unroll
        for (int j = 0; j < 8; ++j) {
            float v0 = bf2f((ushort_t)mv[j]) * mk[j];
            ushort_t wb = f2bf(v0);
            wv[j] = (short)wb;
            float v = bf2f(wb);          // use the rounded value consistently
            float nm = fmaxf(mx[j], v);
            sm[j] = sm[j] * __expf(mx[j] - nm) + __expf(v - nm);
            mx[j] = nm;
        }
        *(sh8*)(m + off) = wv;
    }
    #pragma unroll
    for (int j = 0; j < 8; ++j) {
        pmax[(size_t)(c0 + j) * NCH + chunk] = mx[j];
        psum[(size_t)(c0 + j) * NCH + chunk] = sm[j];
    }
}

__global__ __launch_bounds__(256)
void smax_pass2(const float* __restrict__ pmax, const float* __restrict__ psum,
                float* __restrict__ cmax, float* __restrict__ cinv)
{
    int col = blockIdx.x, t = threadIdx.x;
    float m = pmax[(size_t)col * NCH + t];
    float s = psum[(size_t)col * NCH + t];

    __shared__ float red[8];
    int w = t >> 6, l = t & 63;

    float mx = m;
    #pragma unroll
    for (int off = 32; off; off >>= 1) mx = fmaxf(mx, __shfl_down(mx, off));
    if (!l) red[w] = mx;
    __syncthreads();
    mx = fmaxf(fmaxf(red[0], red[1]), fmaxf(red[2], red[3]));
    __syncthreads();

    float sc = s * __expf(m - mx);
    #pragma unroll
    for (int off = 32; off; off >>= 1) sc += __shfl_down(sc, off);
    if (!l) red[4 + w] = sc;
    __syncthreads();
    if (t == 0) {
        float total = red[4] + red[5] + red[6] + red[7];
        cmax[col] = mx;
        cinv[col] = 1.f / total;
    }
}

__global__ __launch_bounds__(256)
void smax_pass3(const ushort_t* __restrict__ m,
                const float* __restrict__ cmax, const float* __restrict__ cinv,
                ushort_t* __restrict__ h)
{
    size_t idx = ((size_t)blockIdx.x * 256 + threadIdx.x) * 8;
    int col0 = (int)(idx & (S_DIM - 1));
    sh8 mv = *(const sh8*)(m + idx);
    sh8 r;
    #pragma unroll
    for (int j = 0; j < 8; ++j) {
        int c = col0 + j;
        float v = bf2f((ushort_t)mv[j]);
        r[j] = (short)f2bf(__expf(v - cmax[c]) * cinv[c]);
    }
    *(sh8*)(h + idx) = r;
}

// ---------------------------------------------------------------------------
// LayerNorm( sum(parts) + pbias + resid ) over D=1024, one row per block.
// ---------------------------------------------------------------------------
template<int NS, bool WB>
__global__ __launch_bounds__(256)
void add_ln_sk(const ushort_t* __restrict__ parts, const float* __restrict__ pbias,
               const float* __restrict__ resid, const float* __restrict__ g,
               const float* __restrict__ be,
               float* __restrict__ of, ushort_t* __restrict__ ob)
{
    const int D = D_DIM;
    const size_t SD = (size_t)S_DIM * D_DIM;
    int row = blockIdx.x, tid = threadIdx.x;
    size_t base = (size_t)row * D + tid * 4;

    float4 vr = *(const float4*)(resid + base);
    float4 vbi = ((const float4*)pbias)[tid];
    float x0 = vr.x + vbi.x, x1 = vr.y + vbi.y, x2 = vr.z + vbi.z, x3 = vr.w + vbi.w;
    #pragma unroll
    for (int p = 0; p < NS; ++p) {
        sh4 v = *(const sh4*)(parts + p * SD + base);
        x0 += bf2f((ushort_t)v[0]); x1 += bf2f((ushort_t)v[1]);
        x2 += bf2f((ushort_t)v[2]); x3 += bf2f((ushort_t)v[3]);
    }

    float s = x0 + x1 + x2 + x3;
    float q = x0 * x0 + x1 * x1 + x2 * x2 + x3 * x3;
    #pragma unroll
    for (int off = 32; off; off >>= 1) {
        s += __shfl_down(s, off);
        q += __shfl_down(q, off);
    }
    __shared__ float red[8];
    int w = tid >> 6, l = tid & 63;
    if (!l) { red[w] = s; red[4 + w] = q; }
    __syncthreads();
    s = red[0] + red[1] + red[2] + red[3];
    q = red[4] + red[5] + red[6] + red[7];
    float mu = s * (1.f / D);
    float rstd = rsqrtf(q * (1.f / D) - mu * mu + 1e-5f);
    float4 vg  = ((const float4*)g)[tid];
    float4 vbe = ((const float4*)be)[tid];
    float y0 = (x0 - mu) * rstd * vg.x + vbe.x;
    float y1 = (x1 - mu) * rstd * vg.y + vbe.y;
    float y2 = (x2 - mu) * rstd * vg.z + vbe.z;
    float y3 = (x3 - mu) * rstd * vg.w + vbe.w;
    float4 r; r.x = y0; r.y = y1; r.z = y2; r.w = y3;
    *(float4*)(of + base) = r;
    if (WB) {
        sh4 rb;
        rb[0] = (short)f2bf(y0); rb[1] = (short)f2bf(y1);
        rb[2] = (short)f2bf(y2); rb[3] = (short)f2bf(y3);
        *(sh4*)(ob + base) = rb;
    }
}

// ---------------------------------------------------------------------------
extern "C" void kernel_launch(void* const* d_in, const int* in_sizes, int n_in,
                              void* d_out, int out_size, void* d_ws, size_t ws_size,
                              hipStream_t stream)
{
    const float* query = (const float*)d_in[0];
    const float* key_  = (const float*)d_in[1];
    const float* value = (const float*)d_in[2];
    const float* mask  = (const float*)d_in[3];
    const float* Wq = (const float*)d_in[4];  const float* bq = (const float*)d_in[5];
    const float* Wk = (const float*)d_in[6];  const float* bk = (const float*)d_in[7];
    const float* Wv = (const float*)d_in[8];  const float* bv = (const float*)d_in[9];
    const float* Wo = (const float*)d_in[10]; const float* bo = (const float*)d_in[11];
    const float* g1 = (const float*)d_in[12]; const float* be1 = (const float*)d_in[13];
    const float* W1 = (const float*)d_in[14]; const float* bf1 = (const float*)d_in[15];
    const float* W2 = (const float*)d_in[16]; const float* bf2 = (const float*)d_in[17];
    const float* g2 = (const float*)d_in[18]; const float* be2 = (const float*)d_in[19];

    const size_t MB = 1ull << 20;
    char* ws = (char*)d_ws;
    ushort_t* WqT = (ushort_t*)(ws);             // [0,2)
    ushort_t* WkT = (ushort_t*)(ws + 2 * MB);    // [2,4)
    ushort_t* WvT = (ushort_t*)(ws + 4 * MB);    // [4,6)
    ushort_t* WoT = (ushort_t*)(ws + 6 * MB);    // [6,8)
    ushort_t* W1T = (ushort_t*)(ws + 8 * MB);    // [8,16)   [F][D]
    ushort_t* W2T = (ushort_t*)(ws + 16 * MB);   // [16,24)  [D][F]
    ushort_t* qin = (ushort_t*)(ws + 24 * MB);   // [24,32)
    ushort_t* kin = (ushort_t*)(ws + 32 * MB);   // [32,40)
    ushort_t* vin = (ushort_t*)(ws + 40 * MB);   // [40,48)
    ushort_t* qb  = (ushort_t*)(ws + 48 * MB);   // [48,56)
    ushort_t* kb  = (ushort_t*)(ws + 56 * MB);   // [56,64)
    ushort_t* vb  = (ushort_t*)(ws + 64 * MB);   // [64,72)
    ushort_t* vT  = (ushort_t*)(ws + 72 * MB);   // [72,80)  [D][S]
    ushort_t* msc = (ushort_t*)(ws + 80 * MB);   // [80,112) scores -> masked (in place)
    ushort_t* hb  = (ushort_t*)(ws + 112 * MB);  // [112,144)
    float*   pmax = (float*)(ws + 144 * MB);     // [144,148) [S][NCH]
    float*   psum = (float*)(ws + 148 * MB);     // [148,152)
    float*   cmax = (float*)(ws + 152 * MB);
    float*   cinv = (float*)(ws + 152 * MB + 64 * 1024);
    // reused regions
    ushort_t* pts1  = (ushort_t*)(ws + 80 * MB); // h@v partials 4x8MB over msc
    ushort_t* apb   = (ushort_t*)(ws + 24 * MB); // attn_pre bf16 over qin
    ushort_t* pts2  = (ushort_t*)(ws + 80 * MB); // attn@Wo partials 2x8MB
    float*    n1f   = (float*)(ws + 48 * MB);    // over qb+kb
    ushort_t* n1b   = (ushort_t*)(ws + 64 * MB); // over vb
    ushort_t* mid   = (ushort_t*)(ws + 112 * MB);// [S][F] bf16 over hb
    ushort_t* pts3  = (ushort_t*)(ws + 80 * MB); // ff partials 4x8MB

    const int S = S_DIM, D = D_DIM, F = F_DIM;

    // 1. weights -> bf16 transposed
    transpose4_f32_bf16<<<dim3(D / 32, D / 32, 4), 256, 0, stream>>>(
        Wq, Wk, Wv, Wo, WqT, WkT, WvT, WoT);
    transpose_f32_bf16<<<dim3(F / 32, D / 32), 256, 0, stream>>>(W1, W1T, D, F);
    transpose_f32_bf16<<<dim3(D / 32, F / 32), 256, 0, stream>>>(W2, W2T, F, D);

    // 2. activations -> bf16
    cvt_bf16_3<<<dim3(S * D / 8 / 256, 3), 256, 0, stream>>>(
        query, key_, value, qin, kin, vin);

    // 3. batched q,k,v projections
    qkv_gemm<<<dim3(S / BM, D / BN, 3), 256, 0, stream>>>(
        qin, kin, vin, WqT, WkT, WvT, bq, bk, bv, qb, kb, vb, S, D, D);

    // 4. v^T bf16 [D][S]
    transpose_bf16<<<dim3(D / 32, S / 32), 256, 0, stream>>>(vb, vT, S, D);

    // 5. scaled scores: (q @ k^T) / sqrt(D)
    gemm_bt<false, false, true, true><<<dim3(S / BM, S / BN), 256, 0, stream>>>(
        qb, kb, nullptr, nullptr, msc, S, S, D, 0.03125f);

    // 6. column softmax; pass1 masks in place, pass3 reads masked only
    smax_pass1<<<dim3(S / 2048, NCH), 256, 0, stream>>>(msc, mask, pmax, psum);
    smax_pass2<<<S, 256, 0, stream>>>(pmax, psum, cmax, cinv);
    smax_pass3<<<(size_t)S * S / 8 / 256, 256, 0, stream>>>(msc, cmax, cinv, hb);

    // 7. attn_pre = h @ v  — 4-way split-K
    gemm_bt_sk<<<dim3(S / BM, D / BN, 4), 256, 0, stream>>>(hb, vT, pts1, S, D, S, S / 4);
    reduce_sk<4><<<S * D / 2048, 256, 0, stream>>>(pts1, apb, (size_t)S * D);

    // 8. attn partials = attn_pre @ Wo — 2-way split-K (reduction fused in LN1)
    gemm_bt_sk<<<dim3(S / BM, D / BN, 2), 256, 0, stream>>>(apb, WoT, pts2, S, D, D, D / 2);

    // 9. n1 = LN(sum(pts2) + bo + query)
    add_ln_sk<2, true><<<S, 256, 0, stream>>>(pts2, bo, query, g1, be1, n1f, n1b);

    // 10. mid = relu(n1 @ W1 + bf1)
    gemm_bt<true, true, false, true><<<dim3(S / BM, F / BN), 256, 0, stream>>>(
        n1b, W1T, bf1, nullptr, mid, S, F, D, 1.f);

    // 11. ff partials = mid @ W2 — 4-way split-K (reduction fused in LN2)
    gemm_bt_sk<<<dim3(S / BM, D / BN, 4), 256, 0, stream>>>(mid, W2T, pts3, S, D, F, F / 4);

    // 12. out = LN(sum(pts3) + bf2 + n1)
    add_ln_sk<4, false><<<S, 256, 0, stream>>>(pts3, bf2, n1f, g2, be2,
                                               (float*)d_out, nullptr);
}

// Round 9
// 335.701 us; speedup vs baseline: 1.4135x; 1.0683x over previous
//
#include <hip/hip_runtime.h>
#include <hip/hip_bf16.h>

#define S_DIM 4096
#define D_DIM 1024
#define F_DIM 4096

typedef unsigned short ushort_t;
typedef __attribute__((ext_vector_type(8))) short sh8;
typedef __attribute__((ext_vector_type(4))) short sh4;
typedef __attribute__((ext_vector_type(4))) float fx4;

__device__ __forceinline__ ushort_t f2bf(float f) {
    union { float f; unsigned u; } v; v.f = f;
    unsigned r = v.u + 0x7fffu + ((v.u >> 16) & 1u);
    return (ushort_t)(r >> 16);
}
__device__ __forceinline__ float bf2f(ushort_t u) {
    union { unsigned u; float f; } v; v.u = ((unsigned)u) << 16;
    return v.f;
}

typedef const __attribute__((address_space(1))) void* gvp;
typedef __attribute__((address_space(3))) void* svp;
__device__ __forceinline__ void gload_lds16(const void* g, void* l) {
    __builtin_amdgcn_global_load_lds((gvp)g, (svp)l, 16, 0, 0);
}

// ---------------------------------------------------------------------------
// 128x128 bf16 GEMM (4 waves) — round-7-verified T3+T4 pipeline:
// 3 LDS buffers, stage 2 K-steps ahead, one barrier/K-step, vmcnt(4) steady.
// Used for the small GEMMs (qkv projections, attn@Wo).
// ---------------------------------------------------------------------------
#define BM 128
#define BN 128
#define BK 32
#define LDS_BUF 16384   // bytes per buffer: A 8KB + B 8KB

template<bool BIAS, bool RELU, bool SCALE, bool OUTBF, bool SPLITK>
__device__ __forceinline__
void gemm_body(const ushort_t* A, const ushort_t* Bt,
               const float* bias,
               float* Cf, ushort_t* Cb,
               int M, int N, int K, int kBeg, int kEnd, float scale)
{
    __shared__ ushort_t lds[3 * (BM * BK + BN * BK)];   // 48 KiB
    const int tid = threadIdx.x;
    const int bm = blockIdx.x, bn = blockIdx.y;
    const int w  = tid >> 6, l = tid & 63;
    const int wm = w >> 1, wn = w & 1;

    fx4 acc[4][4] = {};

    const ushort_t* Ag = A  + (size_t)(bm * BM) * K;
    const ushort_t* Bg = Bt + (size_t)(bn * BN) * K;

    const int srow = tid >> 2;
    const int scs  = (tid & 3) ^ (srow & 3);   // pre-swizzled global chunk

    auto stage = [&](int b, int k0) {
        char* base = (char*)lds + b * LDS_BUF;
        #pragma unroll
        for (int c = 0; c < 2; ++c) {
            int row = c * 64 + srow;           // row&3 == srow&3
            gload_lds16(Ag + (size_t)row * K + k0 + scs * 8,
                        base + c * 4096 + tid * 16);
            gload_lds16(Bg + (size_t)row * K + k0 + scs * 8,
                        base + 8192 + c * 4096 + tid * 16);
        }
    };

    const int nt = (kEnd - kBeg) / BK;

    stage(0, kBeg);
    if (nt > 1) {
        stage(1, kBeg + BK);
        asm volatile("s_waitcnt vmcnt(4)" ::: "memory");
    } else {
        asm volatile("s_waitcnt vmcnt(0)" ::: "memory");
    }
    __builtin_amdgcn_s_barrier();
    __builtin_amdgcn_sched_barrier(0);

    int cur = 0;
    for (int t = 0; t < nt; ++t) {
        int stg = cur + 2; if (stg >= 3) stg -= 3;
        if (t + 2 < nt) stage(stg, kBeg + (t + 2) * BK);

        char* lbase = (char*)lds + cur * LDS_BUF;
        sh8 af[4], bfr[4];
        #pragma unroll
        for (int q = 0; q < 4; ++q) {
            int ra = wm * 64 + q * 16 + (l & 15);
            int ca = (l >> 4) ^ (ra & 3);
            af[q]  = *(const sh8*)(lbase + ra * 64 + ca * 16);
            int rb = wn * 64 + q * 16 + (l & 15);
            int cb = (l >> 4) ^ (rb & 3);
            bfr[q] = *(const sh8*)(lbase + 8192 + rb * 64 + cb * 16);
        }
        #pragma unroll
        for (int i = 0; i < 4; ++i)
            #pragma unroll
            for (int j = 0; j < 4; ++j)
                acc[i][j] = __builtin_amdgcn_mfma_f32_16x16x32_bf16(
                                af[i], bfr[j], acc[i][j], 0, 0, 0);

        asm volatile("s_waitcnt lgkmcnt(0)" ::: "memory");
        if (t + 2 < nt)      asm volatile("s_waitcnt vmcnt(4)" ::: "memory");
        else if (t + 1 < nt) asm volatile("s_waitcnt vmcnt(0)" ::: "memory");
        if (t + 1 < nt) {
            __builtin_amdgcn_s_barrier();
            __builtin_amdgcn_sched_barrier(0);
        }
        cur = cur + 1; if (cur == 3) cur = 0;
    }

    if (SPLITK) Cb += (size_t)blockIdx.z * M * N;

    const int crow0 = bm * BM + wm * 64;
    const int ccol0 = bn * BN + wn * 64;
    #pragma unroll
    for (int i = 0; i < 4; ++i) {
        #pragma unroll
        for (int j = 0; j < 4; ++j) {
            int col = ccol0 + j * 16 + (l & 15);
            float bia = BIAS ? bias[col] : 0.f;
            #pragma unroll
            for (int r = 0; r < 4; ++r) {
                int row = crow0 + i * 16 + (l >> 4) * 4 + r;
                float v = acc[i][j][r] + bia;
                if (SCALE) v *= scale;
                if (RELU) v = fmaxf(v, 0.f);
                if (OUTBF) Cb[(size_t)row * N + col] = f2bf(v);
                else       Cf[(size_t)row * N + col] = v;
            }
        }
    }
}

template<bool BIAS, bool RELU, bool SCALE, bool OUTBF>
__global__ __launch_bounds__(256)
void gemm_bt(const ushort_t* __restrict__ A, const ushort_t* __restrict__ Bt,
             const float* __restrict__ bias,
             float* __restrict__ Cf, ushort_t* __restrict__ Cb,
             int M, int N, int K, float scale)
{
    gemm_body<BIAS, RELU, SCALE, OUTBF, false>(A, Bt, bias, Cf, Cb,
                                               M, N, K, 0, K, scale);
}

__global__ __launch_bounds__(256)
void gemm_bt_sk(const ushort_t* __restrict__ A, const ushort_t* __restrict__ Bt,
                ushort_t* __restrict__ Cpart, int M, int N, int K, int Ks)
{
    int z = blockIdx.z;
    gemm_body<false, false, false, true, true>(A, Bt, nullptr,
                                               nullptr, Cpart,
                                               M, N, K, z * Ks, z * Ks + Ks, 1.f);
}

__global__ __launch_bounds__(256)
void qkv_gemm(const ushort_t* qin, const ushort_t* kin, const ushort_t* vin,
              const ushort_t* WqT, const ushort_t* WkT, const ushort_t* WvT,
              const float* bq, const float* bk, const float* bv,
              ushort_t* qb, ushort_t* kb, ushort_t* vb, int M, int N, int K)
{
    const ushort_t* A; const ushort_t* Bt; const float* bias; ushort_t* C;
    if (blockIdx.z == 0)      { A = qin; Bt = WqT; bias = bq; C = qb; }
    else if (blockIdx.z == 1) { A = kin; Bt = WkT; bias = bk; C = kb; }
    else                      { A = vin; Bt = WvT; bias = bv; C = vb; }
    gemm_body<true, false, false, true, false>(A, Bt, bias,
                                               nullptr, C, M, N, K, 0, K, 1.f);
}

// ---------------------------------------------------------------------------
// 256x256 bf16 GEMM (8 waves, 512 thr) — SAME sync schedule as the 128² body
// (3 bufs, stage 2 ahead, 4 gload_lds/thread/K-step, vmcnt(4) steady, one
// barrier/K-step, all-explicit waits). Parameter scale-up of the verified
// template: per-wave 128x64 output = 8x4 fragments, 32 MFMA : 12 ds_read.
// LDS 3 x 32KB = 96KB -> 1 block/CU. Used for the 4 big GEMMs.
// ---------------------------------------------------------------------------
#define G2_BM 256
#define G2_BN 256
#define G2_BUF 32768     // bytes: A 16KB + B 16KB

template<bool BIAS, bool RELU, bool SCALE, bool OUTBF, bool SPLITK>
__device__ __forceinline__
void gemm256_body(const ushort_t* A, const ushort_t* Bt,
                  const float* bias,
                  float* Cf, ushort_t* Cb,
                  int M, int N, int K, int kBeg, int kEnd, float scale)
{
    __shared__ ushort_t lds[3 * (G2_BM * BK + G2_BN * BK)];   // 96 KiB
    const int tid = threadIdx.x;            // 0..511
    const int bm = blockIdx.x, bn = blockIdx.y;
    const int w  = tid >> 6, l = tid & 63;
    const int wm = w >> 2, wn = w & 3;      // 2 x 4 waves

    fx4 acc[8][4] = {};

    const ushort_t* Ag = A  + (size_t)(bm * G2_BM) * K;
    const ushort_t* Bg = Bt + (size_t)(bn * G2_BN) * K;

    auto stage = [&](int b, int k0) {
        char* base = (char*)lds + b * G2_BUF;
        #pragma unroll
        for (int c = 0; c < 2; ++c) {
            int idx = c * 512 + tid;        // 0..1023 : 256 rows x 4 chunks
            int row = idx >> 2;
            int cs  = idx & 3;
            gload_lds16(Ag + (size_t)row * K + k0 + cs * 8,
                        base + idx * 16);
            gload_lds16(Bg + (size_t)row * K + k0 + cs * 8,
                        base + 16384 + idx * 16);
        }
    };

    const int nt = (kEnd - kBeg) / BK;

    stage(0, kBeg);
    if (nt > 1) {
        stage(1, kBeg + BK);
        asm volatile("s_waitcnt vmcnt(4)" ::: "memory");
    } else {
        asm volatile("s_waitcnt vmcnt(0)" ::: "memory");
    }
    __builtin_amdgcn_s_barrier();
    __builtin_amdgcn_sched_barrier(0);

    int cur = 0;
    for (int t = 0; t < nt; ++t) {
        int stg = cur + 2; if (stg >= 3) stg -= 3;
        if (t + 2 < nt) stage(stg, kBeg + (t + 2) * BK);

        char* lbase = (char*)lds + cur * G2_BUF;
        sh8 af[8], bfr[4];
        #pragma unroll
        for (int q = 0; q < 8; ++q) {
            int ra = wm * 128 + q * 16 + (l & 15);
            af[q] = *(const sh8*)(lbase + ra * 64 + (l >> 4) * 16);
        }
        #pragma unroll
        for (int j = 0; j < 4; ++j) {
            int rb = wn * 64 + j * 16 + (l & 15);
            bfr[j] = *(const sh8*)(lbase + 16384 + rb * 64 + (l >> 4) * 16);
        }
        #pragma unroll
        for (int i = 0; i < 8; ++i)
            #pragma unroll
            for (int j = 0; j < 4; ++j)
                acc[i][j] = __builtin_amdgcn_mfma_f32_16x16x32_bf16(
                                af[i], bfr[j], acc[i][j], 0, 0, 0);

        asm volatile("s_waitcnt lgkmcnt(0)" ::: "memory");
        if (t + 2 < nt)      asm volatile("s_waitcnt vmcnt(4)" ::: "memory");
        else if (t + 1 < nt) asm volatile("s_waitcnt vmcnt(0)" ::: "memory");
        if (t + 1 < nt) {
            __builtin_amdgcn_s_barrier();
            __builtin_amdgcn_sched_barrier(0);
        }
        cur = cur + 1; if (cur == 3) cur = 0;
    }

    if (SPLITK) Cb += (size_t)blockIdx.z * M * N;

    const int crow0 = bm * G2_BM + wm * 128;
    const int ccol0 = bn * G2_BN + wn * 64;
    #pragma unroll
    for (int i = 0; i < 8; ++i) {
        #pragma unroll
        for (int j = 0; j < 4; ++j) {
            int col = ccol0 + j * 16 + (l & 15);
            float bia = BIAS ? bias[col] : 0.f;
            #pragma unroll
            for (int r = 0; r < 4; ++r) {
                int row = crow0 + i * 16 + (l >> 4) * 4 + r;
                float v = acc[i][j][r] + bia;
                if (SCALE) v *= scale;
                if (RELU) v = fmaxf(v, 0.f);
                if (OUTBF) Cb[(size_t)row * N + col] = f2bf(v);
                else       Cf[(size_t)row * N + col] = v;
            }
        }
    }
}

template<bool BIAS, bool RELU, bool SCALE, bool OUTBF>
__global__ __launch_bounds__(512)
void gemm256_bt(const ushort_t* __restrict__ A, const ushort_t* __restrict__ Bt,
                const float* __restrict__ bias,
                float* __restrict__ Cf, ushort_t* __restrict__ Cb,
                int M, int N, int K, float scale)
{
    gemm256_body<BIAS, RELU, SCALE, OUTBF, false>(A, Bt, bias, Cf, Cb,
                                                  M, N, K, 0, K, scale);
}

__global__ __launch_bounds__(512)
void gemm256_bt_sk(const ushort_t* __restrict__ A, const ushort_t* __restrict__ Bt,
                   ushort_t* __restrict__ Cpart, int M, int N, int K, int Ks)
{
    int z = blockIdx.z;
    gemm256_body<false, false, false, true, true>(A, Bt, nullptr,
                                                  nullptr, Cpart,
                                                  M, N, K, z * Ks, z * Ks + Ks, 1.f);
}

// sum NS bf16 partial matrices, write bf16
template<int NS>
__global__ __launch_bounds__(256)
void reduce_sk(const ushort_t* __restrict__ parts, ushort_t* __restrict__ ob,
               size_t MN)
{
    size_t idx = ((size_t)blockIdx.x * 256 + threadIdx.x) * 8;
    float s[8] = {0.f, 0.f, 0.f, 0.f, 0.f, 0.f, 0.f, 0.f};
    #pragma unroll
    for (int p = 0; p < NS; ++p) {
        sh8 v = *(const sh8*)(parts + (size_t)p * MN + idx);
        #pragma unroll
        for (int j = 0; j < 8; ++j) s[j] += bf2f((ushort_t)v[j]);
    }
    sh8 r;
    #pragma unroll
    for (int j = 0; j < 8; ++j) r[j] = (short)f2bf(s[j]);
    *(sh8*)(ob + idx) = r;
}

// ---------------------------------------------------------------------------
// Transposes / converts
// ---------------------------------------------------------------------------
__global__ __launch_bounds__(256)
void transpose_f32_bf16(const float* __restrict__ in, ushort_t* __restrict__ out,
                        int R, int C)
{
    __shared__ float t[32][33];
    int bc = blockIdx.x * 32, br = blockIdx.y * 32;
    int tx = threadIdx.x & 31, ty = threadIdx.x >> 5;
    #pragma unroll
    for (int i = 0; i < 32; i += 8)
        t[ty + i][tx] = in[(size_t)(br + ty + i) * C + bc + tx];
    __syncthreads();
    #pragma unroll
    for (int i = 0; i < 32; i += 8)
        out[(size_t)(bc + ty + i) * R + br + tx] = f2bf(t[tx][ty + i]);
}

__global__ __launch_bounds__(256)
void transpose4_f32_bf16(const float* w0, const float* w1,
                         const float* w2, const float* w3,
                         ushort_t* o0, ushort_t* o1, ushort_t* o2, ushort_t* o3)
{
    const int R = D_DIM, C = D_DIM;
    const float* in; ushort_t* out;
    if (blockIdx.z == 0)      { in = w0; out = o0; }
    else if (blockIdx.z == 1) { in = w1; out = o1; }
    else if (blockIdx.z == 2) { in = w2; out = o2; }
    else                      { in = w3; out = o3; }
    __shared__ float t[32][33];
    int bc = blockIdx.x * 32, br = blockIdx.y * 32;
    int tx = threadIdx.x & 31, ty = threadIdx.x >> 5;
    #pragma unroll
    for (int i = 0; i < 32; i += 8)
        t[ty + i][tx] = in[(size_t)(br + ty + i) * C + bc + tx];
    __syncthreads();
    #pragma unroll
    for (int i = 0; i < 32; i += 8)
        out[(size_t)(bc + ty + i) * R + br + tx] = f2bf(t[tx][ty + i]);
}

__global__ __launch_bounds__(256)
void transpose_bf16(const ushort_t* __restrict__ in, ushort_t* __restrict__ out,
                    int R, int C)
{
    __shared__ ushort_t t[32][33];
    int bc = blockIdx.x * 32, br = blockIdx.y * 32;
    int tx = threadIdx.x & 31, ty = threadIdx.x >> 5;
    #pragma unroll
    for (int i = 0; i < 32; i += 8)
        t[ty + i][tx] = in[(size_t)(br + ty + i) * C + bc + tx];
    __syncthreads();
    #pragma unroll
    for (int i = 0; i < 32; i += 8)
        out[(size_t)(bc + ty + i) * R + br + tx] = t[tx][ty + i];
}

__global__ __launch_bounds__(256)
void cvt_bf16_3(const float* a, const float* b, const float* c,
                ushort_t* oa, ushort_t* ob, ushort_t* oc)
{
    const float* in; ushort_t* out;
    if (blockIdx.y == 0)      { in = a; out = oa; }
    else if (blockIdx.y == 1) { in = b; out = ob; }
    else                      { in = c; out = oc; }
    int i = (blockIdx.x * 256 + threadIdx.x) * 8;
    const float4* p = (const float4*)(in + i);
    float4 x = p[0], y = p[1];
    sh8 r;
    r[0] = (short)f2bf(x.x); r[1] = (short)f2bf(x.y);
    r[2] = (short)f2bf(x.z); r[3] = (short)f2bf(x.w);
    r[4] = (short)f2bf(y.x); r[5] = (short)f2bf(y.y);
    r[6] = (short)f2bf(y.z); r[7] = (short)f2bf(y.w);
    *(sh8*)(out + i) = r;
}

// ---------------------------------------------------------------------------
// Column softmax (axis 0). pass1 masks in place; pass3 reads masked only.
// ---------------------------------------------------------------------------
#define NCH 256
#define ROWS_PER_CH (S_DIM / NCH)   // 16

__global__ __launch_bounds__(256)
void smax_pass1(ushort_t* __restrict__ m, const float* __restrict__ mask,
                float* __restrict__ pmax, float* __restrict__ psum)
{
    int c0 = (blockIdx.x * 256 + threadIdx.x) * 8;
    int chunk = blockIdx.y;
    int r0 = chunk * ROWS_PER_CH;

    float mx[8], sm[8];
    #pragma unroll
    for (int j = 0; j < 8; ++j) { mx[j] = -1e30f; sm[j] = 0.f; }

    for (int i = 0; i < ROWS_PER_CH; ++i) {
        size_t off = (size_t)(r0 + i) * S_DIM + c0;
        sh8 mv = *(const sh8*)(m + off);
        float4 k0 = ((const float4*)(mask + off))[0];
        float4 k1 = ((const float4*)(mask + off))[1];
        float mk[8] = {k0.x, k0.y, k0.z, k0.w, k1.x, k1.y, k1.z, k1.w};
        sh8 wv;
        #pragma unroll
        for (int j = 0; j < 8; ++j) {
            float v0 = bf2f((ushort_t)mv[j]) * mk[j];
            ushort_t wb = f2bf(v0);
            wv[j] = (short)wb;
            float v = bf2f(wb);
            float nm = fmaxf(mx[j], v);
            sm[j] = sm[j] * __expf(mx[j] - nm) + __expf(v - nm);
            mx[j] = nm;
        }
        *(sh8*)(m + off) = wv;
    }
    #pragma unroll
    for (int j = 0; j < 8; ++j) {
        pmax[(size_t)(c0 + j) * NCH + chunk] = mx[j];
        psum[(size_t)(c0 + j) * NCH + chunk] = sm[j];
    }
}

__global__ __launch_bounds__(256)
void smax_pass2(const float* __restrict__ pmax, const float* __restrict__ psum,
                float* __restrict__ cmax, float* __restrict__ cinv)
{
    int col = blockIdx.x, t = threadIdx.x;
    float m = pmax[(size_t)col * NCH + t];
    float s = psum[(size_t)col * NCH + t];

    __shared__ float red[8];
    int w = t >> 6, l = t & 63;

    float mx = m;
    #pragma unroll
    for (int off = 32; off; off >>= 1) mx = fmaxf(mx, __shfl_down(mx, off));
    if (!l) red[w] = mx;
    __syncthreads();
    mx = fmaxf(fmaxf(red[0], red[1]), fmaxf(red[2], red[3]));
    __syncthreads();

    float sc = s * __expf(m - mx);
    #pragma unroll
    for (int off = 32; off; off >>= 1) sc += __shfl_down(sc, off);
    if (!l) red[4 + w] = sc;
    __syncthreads();
    if (t == 0) {
        float total = red[4] + red[5] + red[6] + red[7];
        cmax[col] = mx;
        cinv[col] = 1.f / total;
    }
}

__global__ __launch_bounds__(256)
void smax_pass3(const ushort_t* __restrict__ m,
                const float* __restrict__ cmax, const float* __restrict__ cinv,
                ushort_t* __restrict__ h)
{
    size_t idx = ((size_t)blockIdx.x * 256 + threadIdx.x) * 8;
    int col0 = (int)(idx & (S_DIM - 1));
    sh8 mv = *(const sh8*)(m + idx);
    sh8 r;
    #pragma unroll
    for (int j = 0; j < 8; ++j) {
        int c = col0 + j;
        float v = bf2f((ushort_t)mv[j]);
        r[j] = (short)f2bf(__expf(v - cmax[c]) * cinv[c]);
    }
    *(sh8*)(h + idx) = r;
}

// ---------------------------------------------------------------------------
// LayerNorm( sum(parts) + pbias + resid ) over D=1024, one row per block.
// ---------------------------------------------------------------------------
template<int NS, bool WB>
__global__ __launch_bounds__(256)
void add_ln_sk(const ushort_t* __restrict__ parts, const float* __restrict__ pbias,
               const float* __restrict__ resid, const float* __restrict__ g,
               const float* __restrict__ be,
               float* __restrict__ of, ushort_t* __restrict__ ob)
{
    const int D = D_DIM;
    const size_t SD = (size_t)S_DIM * D_DIM;
    int row = blockIdx.x, tid = threadIdx.x;
    size_t base = (size_t)row * D + tid * 4;

    float4 vr = *(const float4*)(resid + base);
    float4 vbi = ((const float4*)pbias)[tid];
    float x0 = vr.x + vbi.x, x1 = vr.y + vbi.y, x2 = vr.z + vbi.z, x3 = vr.w + vbi.w;
    #pragma unroll
    for (int p = 0; p < NS; ++p) {
        sh4 v = *(const sh4*)(parts + p * SD + base);
        x0 += bf2f((ushort_t)v[0]); x1 += bf2f((ushort_t)v[1]);
        x2 += bf2f((ushort_t)v[2]); x3 += bf2f((ushort_t)v[3]);
    }

    float s = x0 + x1 + x2 + x3;
    float q = x0 * x0 + x1 * x1 + x2 * x2 + x3 * x3;
    #pragma unroll
    for (int off = 32; off; off >>= 1) {
        s += __shfl_down(s, off);
        q += __shfl_down(q, off);
    }
    __shared__ float red[8];
    int w = tid >> 6, l = tid & 63;
    if (!l) { red[w] = s; red[4 + w] = q; }
    __syncthreads();
    s = red[0] + red[1] + red[2] + red[3];
    q = red[4] + red[5] + red[6] + red[7];
    float mu = s * (1.f / D);
    float rstd = rsqrtf(q * (1.f / D) - mu * mu + 1e-5f);
    float4 vg  = ((const float4*)g)[tid];
    float4 vbe = ((const float4*)be)[tid];
    float y0 = (x0 - mu) * rstd * vg.x + vbe.x;
    float y1 = (x1 - mu) * rstd * vg.y + vbe.y;
    float y2 = (x2 - mu) * rstd * vg.z + vbe.z;
    float y3 = (x3 - mu) * rstd * vg.w + vbe.w;
    float4 r; r.x = y0; r.y = y1; r.z = y2; r.w = y3;
    *(float4*)(of + base) = r;
    if (WB) {
        sh4 rb;
        rb[0] = (short)f2bf(y0); rb[1] = (short)f2bf(y1);
        rb[2] = (short)f2bf(y2); rb[3] = (short)f2bf(y3);
        *(sh4*)(ob + base) = rb;
    }
}

// ---------------------------------------------------------------------------
extern "C" void kernel_launch(void* const* d_in, const int* in_sizes, int n_in,
                              void* d_out, int out_size, void* d_ws, size_t ws_size,
                              hipStream_t stream)
{
    const float* query = (const float*)d_in[0];
    const float* key_  = (const float*)d_in[1];
    const float* value = (const float*)d_in[2];
    const float* mask  = (const float*)d_in[3];
    const float* Wq = (const float*)d_in[4];  const float* bq = (const float*)d_in[5];
    const float* Wk = (const float*)d_in[6];  const float* bk = (const float*)d_in[7];
    const float* Wv = (const float*)d_in[8];  const float* bv = (const float*)d_in[9];
    const float* Wo = (const float*)d_in[10]; const float* bo = (const float*)d_in[11];
    const float* g1 = (const float*)d_in[12]; const float* be1 = (const float*)d_in[13];
    const float* W1 = (const float*)d_in[14]; const float* bf1 = (const float*)d_in[15];
    const float* W2 = (const float*)d_in[16]; const float* bf2 = (const float*)d_in[17];
    const float* g2 = (const float*)d_in[18]; const float* be2 = (const float*)d_in[19];

    const size_t MB = 1ull << 20;
    char* ws = (char*)d_ws;
    ushort_t* WqT = (ushort_t*)(ws);             // [0,2)
    ushort_t* WkT = (ushort_t*)(ws + 2 * MB);    // [2,4)
    ushort_t* WvT = (ushort_t*)(ws + 4 * MB);    // [4,6)
    ushort_t* WoT = (ushort_t*)(ws + 6 * MB);    // [6,8)
    ushort_t* W1T = (ushort_t*)(ws + 8 * MB);    // [8,16)   [F][D]
    ushort_t* W2T = (ushort_t*)(ws + 16 * MB);   // [16,24)  [D][F]
    ushort_t* qin = (ushort_t*)(ws + 24 * MB);   // [24,32)
    ushort_t* kin = (ushort_t*)(ws + 32 * MB);   // [32,40)
    ushort_t* vin = (ushort_t*)(ws + 40 * MB);   // [40,48)
    ushort_t* qb  = (ushort_t*)(ws + 48 * MB);   // [48,56)
    ushort_t* kb  = (ushort_t*)(ws + 56 * MB);   // [56,64)
    ushort_t* vb  = (ushort_t*)(ws + 64 * MB);   // [64,72)
    ushort_t* vT  = (ushort_t*)(ws + 72 * MB);   // [72,80)  [D][S]
    ushort_t* msc = (ushort_t*)(ws + 80 * MB);   // [80,112) scores -> masked
    ushort_t* hb  = (ushort_t*)(ws + 112 * MB);  // [112,144)
    float*   pmax = (float*)(ws + 144 * MB);     // [144,148) [S][NCH]
    float*   psum = (float*)(ws + 148 * MB);     // [148,152)
    float*   cmax = (float*)(ws + 152 * MB);
    float*   cinv = (float*)(ws + 152 * MB + 64 * 1024);
    // reused regions
    ushort_t* pts1  = (ushort_t*)(ws + 80 * MB); // h@v partials 4x8MB over msc
    ushort_t* apb   = (ushort_t*)(ws + 24 * MB); // attn_pre bf16 over qin
    ushort_t* pts2  = (ushort_t*)(ws + 80 * MB); // attn@Wo partials 2x8MB
    float*    n1f   = (float*)(ws + 48 * MB);    // over qb+kb
    ushort_t* n1b   = (ushort_t*)(ws + 64 * MB); // over vb
    ushort_t* mid   = (ushort_t*)(ws + 112 * MB);// [S][F] bf16 over hb
    ushort_t* pts3  = (ushort_t*)(ws + 80 * MB); // ff partials 4x8MB

    const int S = S_DIM, D = D_DIM, F = F_DIM;

    // 1. weights -> bf16 transposed
    transpose4_f32_bf16<<<dim3(D / 32, D / 32, 4), 256, 0, stream>>>(
        Wq, Wk, Wv, Wo, WqT, WkT, WvT, WoT);
    transpose_f32_bf16<<<dim3(F / 32, D / 32), 256, 0, stream>>>(W1, W1T, D, F);
    transpose_f32_bf16<<<dim3(D / 32, F / 32), 256, 0, stream>>>(W2, W2T, F, D);

    // 2. activations -> bf16
    cvt_bf16_3<<<dim3(S * D / 8 / 256, 3), 256, 0, stream>>>(
        query, key_, value, qin, kin, vin);

    // 3. batched q,k,v projections (128² kernel, 768 blocks)
    qkv_gemm<<<dim3(S / BM, D / BN, 3), 256, 0, stream>>>(
        qin, kin, vin, WqT, WkT, WvT, bq, bk, bv, qb, kb, vb, S, D, D);

    // 4. v^T bf16 [D][S]
    transpose_bf16<<<dim3(D / 32, S / 32), 256, 0, stream>>>(vb, vT, S, D);

    // 5. scaled scores: (q @ k^T) / sqrt(D)   — 256² kernel, grid (16,16)
    gemm256_bt<false, false, true, true><<<dim3(S / G2_BM, S / G2_BN), 512, 0, stream>>>(
        qb, kb, nullptr, nullptr, msc, S, S, D, 0.03125f);

    // 6. column softmax; pass1 masks in place
    smax_pass1<<<dim3(S / 2048, NCH), 256, 0, stream>>>(msc, mask, pmax, psum);
    smax_pass2<<<S, 256, 0, stream>>>(pmax, psum, cmax, cinv);
    smax_pass3<<<(size_t)S * S / 8 / 256, 256, 0, stream>>>(msc, cmax, cinv, hb);

    // 7. attn_pre = h @ v — 256² kernel, 4-way split-K, grid (16,4,4)
    gemm256_bt_sk<<<dim3(S / G2_BM, D / G2_BN, 4), 512, 0, stream>>>(
        hb, vT, pts1, S, D, S, S / 4);
    reduce_sk<4><<<S * D / 2048, 256, 0, stream>>>(pts1, apb, (size_t)S * D);

    // 8. attn partials = attn_pre @ Wo — 128² kernel, 2-way split-K
    gemm_bt_sk<<<dim3(S / BM, D / BN, 2), 256, 0, stream>>>(apb, WoT, pts2, S, D, D, D / 2);

    // 9. n1 = LN(sum(pts2) + bo + query)
    add_ln_sk<2, true><<<S, 256, 0, stream>>>(pts2, bo, query, g1, be1, n1f, n1b);

    // 10. mid = relu(n1 @ W1 + bf1) — 256² kernel, grid (16,16)
    gemm256_bt<true, true, false, true><<<dim3(S / G2_BM, F / G2_BN), 512, 0, stream>>>(
        n1b, W1T, bf1, nullptr, mid, S, F, D, 1.f);

    // 11. ff partials = mid @ W2 — 256² kernel, 4-way split-K, grid (16,4,4)
    gemm256_bt_sk<<<dim3(S / G2_BM, D / G2_BN, 4), 512, 0, stream>>>(
        mid, W2T, pts3, S, D, F, F / 4);

    // 12. out = LN(sum(pts3) + bf2 + n1)
    add_ln_sk<4, false><<<S, 256, 0, stream>>>(pts3, bf2, n1f, g2, be2,
                                               (float*)d_out, nullptr);
}